// Round 5
// baseline (164.365 us; speedup 1.0000x reference)
//
#include <hip/hip_runtime.h>

// RAFT corr block: B=2, D=256, H=W=80, 4 levels, radius 4.
// avg_pool2(corr) over fmap2's spatial dims == corr with avg-pooled fmap2,
// so the 6400x6400 volume is never materialized.
// R5: bucket-sort pixels by coord cell -> blocks get pixels with overlapping
// tap windows -> L1/L2 reuse instead of random L3 traffic. (R4 + pipeline fix)

typedef _Float16 h2 __attribute__((ext_vector_type(2)));

#define HWDIM 80
#define DCH 256
#define NPIX 12800          // B*H*W
#define NBUCKET 800         // 2 batches * 20x20 cells (4x4 px)

static __device__ __forceinline__ float dot2(h2 a, h2 b, float c) {
#if __has_builtin(__builtin_amdgcn_fdot2)
    return __builtin_amdgcn_fdot2(a, b, c, false);
#else
    return fmaf((float)a[0], (float)b[0], fmaf((float)a[1], (float)b[1], c));
#endif
}

// ---------------- transpose [B,256,6400] fp32 -> [B,6400,256] f16 ----------------
__global__ __launch_bounds__(256) void transpose_f16(const float* __restrict__ src,
                                                     _Float16* __restrict__ dst) {
    __shared__ float tile[256][33];
    int bid = blockIdx.x;
    int b = bid / 200;
    int s0 = (bid % 200) * 32;
    int t = threadIdx.x;
    const float* sb = src + (size_t)b * DCH * (HWDIM * HWDIM);
#pragma unroll 4
    for (int k = 0; k < 32; ++k) {
        int j = t + 256 * k;
        int c = j >> 5, s = j & 31;
        tile[c][s] = sb[(size_t)c * (HWDIM * HWDIM) + s0 + s];
    }
    __syncthreads();
    _Float16* db = dst + ((size_t)b * (HWDIM * HWDIM) + s0) * DCH;
    int p = t & 127;
    int srow = t >> 7;
#pragma unroll 4
    for (int k = 0; k < 16; ++k) {
        int s = 2 * k + srow;
        h2 v;
        v[0] = (_Float16)tile[2 * p][s];
        v[1] = (_Float16)tile[2 * p + 1][s];
        *(h2*)(db + (size_t)s * DCH + 2 * p) = v;
    }
}

// ---------------- 2x2 avg pool on [B,H,W,256] f16 ----------------
__global__ __launch_bounds__(256) void pool2(const _Float16* __restrict__ src,
                                             _Float16* __restrict__ dst,
                                             int Hl, int Wl, int total) {
    int i = blockIdx.x * 256 + threadIdx.x;
    if (i >= total) return;
    int c2 = i & 127;
    int xy = i >> 7;
    int x = xy % Wl;
    int y = (xy / Wl) % Hl;
    int b = xy / (Wl * Hl);
    int Ws = Wl * 2;
    const h2* s = (const h2*)src + (((size_t)(b * (2 * Hl) + 2 * y) * Ws) + 2 * x) * 128 + c2;
    h2 v00 = s[0];
    h2 v01 = s[128];
    h2 v10 = s[(size_t)Ws * 128];
    h2 v11 = s[(size_t)Ws * 128 + 128];
    float r0 = ((float)v00[0] + (float)v01[0] + (float)v10[0] + (float)v11[0]) * 0.25f;
    float r1 = ((float)v00[1] + (float)v01[1] + (float)v10[1] + (float)v11[1]) * 0.25f;
    h2 o;
    o[0] = (_Float16)r0;
    o[1] = (_Float16)r1;
    ((h2*)dst)[i] = o;
}

// ---------------- bucket machinery ----------------
static __device__ __forceinline__ int bucket_of(const float* coords, int n) {
    int b = n / 6400;
    int r = n - b * 6400;
    float cx = coords[(size_t)b * 12800 + r];
    float cy = coords[(size_t)b * 12800 + 6400 + r];
    int ix = min(max((int)floorf(cx), 0), 79);
    int iy = min(max((int)floorf(cy), 0), 79);
    return b * 400 + (iy >> 2) * 20 + (ix >> 2);
}

__global__ __launch_bounds__(1024) void zero_hist(unsigned int* hist) {
    int t = threadIdx.x;
    if (t < NBUCKET) hist[t] = 0u;
}

__global__ __launch_bounds__(1024) void hist_k(const float* __restrict__ coords,
                                               unsigned int* hist) {
    int n = blockIdx.x * 1024 + threadIdx.x;
    if (n >= NPIX) return;
    atomicAdd(&hist[bucket_of(coords, n)], 1u);
}

__global__ __launch_bounds__(1024) void scan_k(const unsigned int* __restrict__ hist,
                                               unsigned int* cursor) {
    __shared__ unsigned int s[1024];
    int t = threadIdx.x;
    s[t] = (t < NBUCKET) ? hist[t] : 0u;
    __syncthreads();
#pragma unroll
    for (int d = 1; d < 1024; d <<= 1) {
        unsigned int v = (t >= d) ? s[t - d] : 0u;
        __syncthreads();
        s[t] += v;
        __syncthreads();
    }
    if (t < NBUCKET) cursor[t] = (t == 0) ? 0u : s[t - 1];
}

__global__ __launch_bounds__(1024) void scatter_k(const float* __restrict__ coords,
                                                  unsigned int* cursor,
                                                  int* __restrict__ sortedIdx,
                                                  int* __restrict__ rank) {
    int n = blockIdx.x * 1024 + threadIdx.x;
    if (n >= NPIX) return;
    unsigned int pos = atomicAdd(&cursor[bucket_of(coords, n)], 1u);
    sortedIdx[pos] = n;
    rank[n] = (int)pos;
}

// ---------------- main: 16 sorted pixels per block ----------------
// 512 threads = 8 waves; 64 (slot,level) tasks remixed across waves.
// Per task: 8 taps in flight (g = lane>>3), 8 lanes/tap, 32 ch/lane,
// software-pipelined group loop with clamped loads.
__global__ __launch_bounds__(512) void corr_sample16(
    const _Float16* __restrict__ f1h,
    const _Float16* __restrict__ f20, const _Float16* __restrict__ f21,
    const _Float16* __restrict__ f22, const _Float16* __restrict__ f23,
    const float* __restrict__ coords, const int* __restrict__ sortedIdx,
    _Float16* __restrict__ scratch) {
    __shared__ float taps[4][16][105];
    __shared__ float fxy[4][16][2];
    __shared__ int sIdx[16];

    int p = blockIdx.x;                    // physical block 0..799
    int l = (p & 7) * 100 + (p >> 3);      // logical: consecutive l share an XCD
    int tid = threadIdx.x;
    if (tid < 16) sIdx[tid] = sortedIdx[l * 16 + tid];
    __syncthreads();

    int w = tid >> 6;
    int lane = tid & 63;
    int g = lane >> 3;                     // tap slot 0..7
    int q = lane & 7;                      // channel chunk 0..7 (32 ch each)

    for (int i = 0; i < 8; ++i) {
        int j = w * 8 + i;
        int px = j & 15;                   // slot within block
        int L = ((j >> 4) + px) & 3;       // each (slot,L) covered exactly once
        int n = sIdx[px];
        int b = n / 6400;
        int r = n - b * 6400;
        int Wl = HWDIM >> L;
        const _Float16* f2 = (L == 0 ? f20 : L == 1 ? f21 : L == 2 ? f22 : f23)
                             + (size_t)b * Wl * Wl * DCH;
        float ls = 1.0f / (float)(1 << L);
        float cx = coords[(size_t)b * 12800 + r];
        float cy = coords[(size_t)b * 12800 + 6400 + r];
        float cxl = cx * ls, cyl = cy * ls;
        float fxf = floorf(cxl), fyf = floorf(cyl);
        int X0 = (int)fxf - 4, Y0 = (int)fyf - 4;
        if (lane == 0) {
            fxy[L][px][0] = cxl - fxf;
            fxy[L][px][1] = cyl - fyf;
        }

        const float4* f1p = (const float4*)(f1h + (size_t)n * DCH);
        float4 f1r[4];
#pragma unroll
        for (int u = 0; u < 4; ++u) f1r[u] = f1p[q + 8 * u];

        int ty0 = g / 10, tx0 = g - ty0 * 10;
        int xi = X0 + tx0, yi = Y0 + ty0;
        bool vcur = ((unsigned)xi < (unsigned)Wl) & ((unsigned)yi < (unsigned)Wl);
        const float4* pc = (const float4*)(f2 + ((size_t)min(max(yi, 0), Wl - 1) * Wl
                                                 + min(max(xi, 0), Wl - 1)) * DCH);
        float4 rc0 = pc[q], rc1 = pc[q + 8], rc2 = pc[q + 16], rc3 = pc[q + 24];

        for (int grp = 0; grp < 13; ++grp) {
            bool vnext = false;
            float4 rn0, rn1, rn2, rn3;
            if (grp < 12) {
                int t = (grp + 1) * 8 + g;
                int ty = t / 10, tx = t - ty * 10;
                int xn = X0 + tx, yn = Y0 + ty;
                vnext = ((unsigned)xn < (unsigned)Wl) & ((unsigned)yn < (unsigned)Wl)
                        & (t < 100);
                const float4* pn = (const float4*)(f2 + ((size_t)min(max(yn, 0), Wl - 1) * Wl
                                                         + min(max(xn, 0), Wl - 1)) * DCH);
                rn0 = pn[q]; rn1 = pn[q + 8]; rn2 = pn[q + 16]; rn3 = pn[q + 24];
            }
            float a0 = 0.f, a1 = 0.f, a2 = 0.f, a3 = 0.f;
            {
                const h2* r0 = (const h2*)&rc0; const h2* e0 = (const h2*)&f1r[0];
                const h2* r1 = (const h2*)&rc1; const h2* e1 = (const h2*)&f1r[1];
                const h2* r2 = (const h2*)&rc2; const h2* e2 = (const h2*)&f1r[2];
                const h2* r3 = (const h2*)&rc3; const h2* e3 = (const h2*)&f1r[3];
#pragma unroll
                for (int u = 0; u < 4; ++u) {
                    a0 = dot2(r0[u], e0[u], a0);
                    a1 = dot2(r1[u], e1[u], a1);
                    a2 = dot2(r2[u], e2[u], a2);
                    a3 = dot2(r3[u], e3[u], a3);
                }
            }
            float acc = (a0 + a1) + (a2 + a3);
            acc = vcur ? acc : 0.f;
            acc += __shfl_xor(acc, 1);
            acc += __shfl_xor(acc, 2);
            acc += __shfl_xor(acc, 4);
            int t = grp * 8 + g;
            if (q == 0 && t < 100) taps[L][px][t] = acc * 0.0625f;  // / sqrt(256)
            // advance the software pipeline (R4's missing lines -> wrong results)
            vcur = vnext;
            rc0 = rn0; rc1 = rn1; rc2 = rn2; rc3 = rn3;
        }
    }
    __syncthreads();

    // epilogue: 4 levels x 81 k x 16 slots -> scratch[l][ch][slot], f16, contiguous
    _Float16* sc = scratch + (size_t)l * 5184;
    for (int idx = tid; idx < 5184; idx += 512) {
        int Le = idx / 1296;
        int r = idx - Le * 1296;
        int k = r >> 4;
        int x = r & 15;
        int a = k / 9;
        int c = k - a * 9;
        float fx = fxy[Le][x][0], fy = fxy[Le][x][1];
        float t00 = taps[Le][x][c * 10 + a];
        float t01 = taps[Le][x][c * 10 + a + 1];
        float t10 = taps[Le][x][(c + 1) * 10 + a];
        float t11 = taps[Le][x][(c + 1) * 10 + a + 1];
        float v = (1.f - fy) * ((1.f - fx) * t00 + fx * t01)
                + fy * ((1.f - fx) * t10 + fx * t11);
        sc[idx] = (_Float16)v;
    }
}

// ---------------- unsort: scratch[rank[n]] -> out[b][ch][n], coalesced writes ----
__global__ __launch_bounds__(256) void unsort_k(const _Float16* __restrict__ scratch,
                                                const int* __restrict__ rank,
                                                float* __restrict__ out) {
    int bid = blockIdx.x;                  // 0..16199 = b(2) x ch(324) x seg(25)
    int seg = bid % 25;
    int ch = (bid / 25) % 324;
    int b = bid / (25 * 324);
    int nl = seg * 256 + threadIdx.x;      // 0..6399
    int rk = rank[b * 6400 + nl];
    float v = (float)scratch[(size_t)(rk >> 4) * 5184 + ch * 16 + (rk & 15)];
    out[((size_t)b * 324 + ch) * 6400 + nl] = v;
}

extern "C" void kernel_launch(void* const* d_in, const int* in_sizes, int n_in,
                              void* d_out, int out_size, void* d_ws, size_t ws_size,
                              hipStream_t stream) {
    const float* fmap1 = (const float*)d_in[0];
    const float* fmap2 = (const float*)d_in[1];
    const float* coords = (const float*)d_in[2];
    float* out = (float*)d_out;
    char* ws = (char*)d_ws;

    _Float16* f1h = (_Float16*)(ws);                   // 6,553,600 B
    _Float16* f20 = (_Float16*)(ws + 6553600);         // 6,553,600 B
    _Float16* f21 = (_Float16*)(ws + 13107200);        // 1,638,400 B
    _Float16* f22 = (_Float16*)(ws + 14745600);        //   409,600 B
    _Float16* f23 = (_Float16*)(ws + 15155200);        //   102,400 B
    unsigned int* hist   = (unsigned int*)(ws + 15257600);   // 3,200 B
    unsigned int* cursor = (unsigned int*)(ws + 15260800);   // 3,200 B
    int* sortedIdx = (int*)(ws + 15264000);            //    51,200 B
    int* rank      = (int*)(ws + 15315200);            //    51,200 B
    _Float16* scratch = (_Float16*)(ws + 15366400);    // 8,294,400 B  (total ~23.7 MB)

    transpose_f16<<<dim3(400), dim3(256), 0, stream>>>(fmap1, f1h);
    transpose_f16<<<dim3(400), dim3(256), 0, stream>>>(fmap2, f20);
    pool2<<<dim3(1600), dim3(256), 0, stream>>>(f20, f21, 40, 40, 2 * 40 * 40 * 128);
    pool2<<<dim3(400), dim3(256), 0, stream>>>(f21, f22, 20, 20, 2 * 20 * 20 * 128);
    pool2<<<dim3(100), dim3(256), 0, stream>>>(f22, f23, 10, 10, 2 * 10 * 10 * 128);

    zero_hist<<<dim3(1), dim3(1024), 0, stream>>>(hist);
    hist_k<<<dim3(13), dim3(1024), 0, stream>>>(coords, hist);
    scan_k<<<dim3(1), dim3(1024), 0, stream>>>(hist, cursor);
    scatter_k<<<dim3(13), dim3(1024), 0, stream>>>(coords, cursor, sortedIdx, rank);

    corr_sample16<<<dim3(800), dim3(512), 0, stream>>>(f1h, f20, f21, f22, f23,
                                                       coords, sortedIdx, scratch);
    unsort_k<<<dim3(16200), dim3(256), 0, stream>>>(scratch, rank, out);
}

// Round 7
// 133.360 us; speedup vs baseline: 1.2325x; 1.2325x over previous
//
#include <hip/hip_runtime.h>

// RAFT corr block: B=2, D=256, H=W=80, 4 levels, radius 4.
// avg_pool2(corr) over fmap2's spatial dims == corr with avg-pooled fmap2.
// R7: R6 (bucket-aligned gather-GEMM via MFMA) + pool2p batch-stride fix
// (PBs/PBd were double-multiplied by 128 -> batch 1 pyramid garbage).

typedef _Float16 h2 __attribute__((ext_vector_type(2)));
typedef _Float16 half8 __attribute__((ext_vector_type(8)));
typedef float f32x4 __attribute__((ext_vector_type(4)));

#define HWDIM 80
#define DCH 256
#define NPIX 12800
#define NBUCKET 800
#define MAXSLOTS 25600       // NPIX + NBUCKET*15, padded
#define MAXBLK 1600

// ---------- transpose [B,256,6400] fp32 -> padded [B,Hp,Wp,256] f16 ----------
__global__ __launch_bounds__(256) void transpose_pad(const float* __restrict__ src,
                                                     _Float16* __restrict__ dst,
                                                     int Wp, int pad, int PBsp) {
    __shared__ float tile[256][33];
    int bid = blockIdx.x;
    int b = bid / 200;
    int s0 = (bid % 200) * 32;
    int t = threadIdx.x;
    const float* sb = src + (size_t)b * DCH * (HWDIM * HWDIM);
#pragma unroll 4
    for (int k = 0; k < 32; ++k) {
        int j = t + 256 * k;
        int c = j >> 5, s = j & 31;
        tile[c][s] = sb[(size_t)c * (HWDIM * HWDIM) + s0 + s];
    }
    __syncthreads();
    int p = t & 127;
    int srow = t >> 7;
#pragma unroll 4
    for (int k = 0; k < 16; ++k) {
        int s = 2 * k + srow;
        int spatial = s0 + s;
        int yy = spatial / 80;
        int xx = spatial - yy * 80;
        h2 v;
        v[0] = (_Float16)tile[2 * p][s];
        v[1] = (_Float16)tile[2 * p + 1][s];
        size_t off = ((size_t)b * PBsp + (size_t)(yy + pad) * Wp + (xx + pad)) * DCH + 2 * p;
        *(h2*)(dst + off) = v;
    }
}

// ---------- 2x2 avg pool, padded src -> padded dst ----------
// PBs/PBd: per-batch size in h2 units (Wp*Wp*128). Used exactly once.
__global__ __launch_bounds__(256) void pool2p(const _Float16* __restrict__ src,
                                              _Float16* __restrict__ dst,
                                              int Hl, int Wl, int Wps, int Wpd,
                                              int PBs, int PBd, int total) {
    int i = blockIdx.x * 256 + threadIdx.x;
    if (i >= total) return;                 // total = B*Hl*Wl*128 (h2 units)
    int c2 = i & 127;
    int xy = i >> 7;
    int x = xy % Wl;
    int y = (xy / Wl) % Hl;
    int b = xy / (Wl * Hl);
    const h2* s = (const h2*)src + (size_t)b * PBs
                + ((size_t)(2 * y + 5) * Wps + (2 * x + 5)) * 128 + c2;
    h2 v00 = s[0];
    h2 v01 = s[128];
    h2 v10 = s[(size_t)Wps * 128];
    h2 v11 = s[(size_t)Wps * 128 + 128];
    float r0 = ((float)v00[0] + (float)v01[0] + (float)v10[0] + (float)v11[0]) * 0.25f;
    float r1 = ((float)v00[1] + (float)v01[1] + (float)v10[1] + (float)v11[1]) * 0.25f;
    h2 o;
    o[0] = (_Float16)r0;
    o[1] = (_Float16)r1;
    *((h2*)dst + (size_t)b * PBd + ((size_t)(y + 5) * Wpd + (x + 5)) * 128 + c2) = o;
}

// ---------- bucket machinery ----------
static __device__ __forceinline__ int bucket_of(const float* coords, int n) {
    int b = n / 6400;
    int r = n - b * 6400;
    float cx = coords[(size_t)b * 12800 + r];
    float cy = coords[(size_t)b * 12800 + 6400 + r];
    int ix = min(max((int)floorf(cx), 0), 79);
    int iy = min(max((int)floorf(cy), 0), 79);
    return b * 400 + (iy >> 2) * 20 + (ix >> 2);
}

__global__ __launch_bounds__(1024) void zero_hist(unsigned int* hist) {
    int t = threadIdx.x;
    if (t < NBUCKET) hist[t] = 0u;
}

__global__ __launch_bounds__(1024) void hist_k(const float* __restrict__ coords,
                                               unsigned int* hist) {
    int n = blockIdx.x * 1024 + threadIdx.x;
    if (n >= NPIX) return;
    atomicAdd(&hist[bucket_of(coords, n)], 1u);
}

// exclusive scan of ceil16(hist) -> pstart, cursor
__global__ __launch_bounds__(1024) void scan_k(const unsigned int* __restrict__ hist,
                                               unsigned int* pstart,
                                               unsigned int* cursor) {
    __shared__ unsigned int s[1024];
    int t = threadIdx.x;
    s[t] = (t < NBUCKET) ? ((hist[t] + 15u) & ~15u) : 0u;
    __syncthreads();
#pragma unroll
    for (int d = 1; d < 1024; d <<= 1) {
        unsigned int v = (t >= d) ? s[t - d] : 0u;
        __syncthreads();
        s[t] += v;
        __syncthreads();
    }
    if (t < NBUCKET) {
        unsigned int e = (t == 0) ? 0u : s[t - 1];
        pstart[t] = e;
        cursor[t] = e;
    }
}

__global__ __launch_bounds__(1024) void scatter_k(const float* __restrict__ coords,
                                                  unsigned int* cursor,
                                                  int* __restrict__ sortedIdxP,
                                                  int* __restrict__ rank) {
    int n = blockIdx.x * 1024 + threadIdx.x;
    if (n >= NPIX) return;
    unsigned int pos = atomicAdd(&cursor[bucket_of(coords, n)], 1u);
    sortedIdxP[pos] = n;
    rank[n] = (int)pos;
}

// duplicate-fill padded slots (after scatter)
__global__ __launch_bounds__(1024) void fill_k(const unsigned int* __restrict__ hist,
                                               const unsigned int* __restrict__ pstart,
                                               int* __restrict__ sortedIdxP) {
    int t = threadIdx.x;
    if (t >= NBUCKET) return;
    unsigned int h = hist[t];
    unsigned int pc = (h + 15u) & ~15u;
    unsigned int base = pstart[t];
    if (h == 0) return;
    int dup = sortedIdxP[base];
    for (unsigned int s = h; s < pc; ++s) sortedIdxP[base + s] = dup;
}

// ---------- main: per-block gather-GEMM via MFMA ----------
// 256 threads = 4 waves. Block l: 16 slots of one bucket. Per level L
// (compile-time unrolled): window rows = Ww x Ww (bounded by the 4x4 cell),
// GEMM G[row,px] = sum_k F2[row][k]*F1[px][k] with mfma_f32_16x16x32_f16,
// then the 81-tap bilinear epilogue reads G.
__global__ __launch_bounds__(256) void corr_mfma(
    const _Float16* __restrict__ f1h,
    const _Float16* __restrict__ f2p0, const _Float16* __restrict__ f2p1,
    const _Float16* __restrict__ f2p2, const _Float16* __restrict__ f2p3,
    const float* __restrict__ coords, const int* __restrict__ sortedIdxP,
    _Float16* __restrict__ scratch) {
    __shared__ float G[176 * 17];          // 11,968 B (max 11 tiles x 16 rows)
    __shared__ float fxS[4][16], fyS[4][16];
    __shared__ int lxS[4][16], lyS[4][16];
    __shared__ int X0cS[4], Y0cS[4], bS;

    int pphys = blockIdx.x;
    int l = (pphys & 7) * 200 + (pphys >> 3);   // XCD swizzle, 1600 % 8 == 0
    int tid = threadIdx.x;
    if (sortedIdxP[l * 16] < 0) return;         // beyond padded slot count
    int lane = tid & 63;
    int wave = tid >> 6;

    // B fragments: f1 channels for the block's 16 pixels, all 8 k-steps.
    // B[k][n]: lane holds n=lane&15, k=(lane>>4)*8+j within each 32-step.
    int npx = sortedIdxP[l * 16 + (lane & 15)];
    const float4* f1p = (const float4*)(f1h + (size_t)npx * DCH);
    half8 bf[8];
#pragma unroll
    for (int kk = 0; kk < 8; ++kk)
        bf[kk] = __builtin_bit_cast(half8, f1p[(lane >> 4) + 4 * kk]);

    if (tid < 64) {
        int px = tid & 15, Lt = tid >> 4;
        int n = sortedIdxP[l * 16 + px];
        int b = n / 6400;
        int r = n - b * 6400;
        float cx = coords[(size_t)b * 12800 + r];
        float cy = coords[(size_t)b * 12800 + 6400 + r];
        float ls = 1.0f / (float)(1 << Lt);
        float cxl = cx * ls, cyl = cy * ls;
        float fxf = floorf(cxl), fyf = floorf(cyl);
        int X0 = (int)fxf - 4, Y0 = (int)fyf - 4;
        int ix = min(max((int)floorf(cx), 0), 79);
        int iy = min(max((int)floorf(cy), 0), 79);
        int X0c = (((ix >> 2) * 4) >> Lt) - 4;
        int Y0c = (((iy >> 2) * 4) >> Lt) - 4;
        lxS[Lt][px] = min(max(X0 - X0c, 0), 3);
        lyS[Lt][px] = min(max(Y0 - Y0c, 0), 3);
        fxS[Lt][px] = cxl - fxf;
        fyS[Lt][px] = cyl - fyf;
        X0cS[Lt] = X0c;
        Y0cS[Lt] = Y0c;
        if (tid == 0) bS = b;
    }
    __syncthreads();
    int b = bS;
    _Float16* sc = scratch + (size_t)l * 5184;

    const int WwT[4]  = {13, 11, 10, 10};
    const int MT[4]   = {169, 121, 100, 100};
    const int NTT[4]  = {11, 8, 7, 7};
    const int MAGT[4] = {161320, 190652, 209716, 209716};  // >= ceil(2^21/Ww)
    const int WpT[4]  = {90, 50, 30, 20};
    const int PBT[4]  = {90 * 90 * 256, 50 * 50 * 256, 30 * 30 * 256, 20 * 20 * 256};

#pragma unroll
    for (int L = 0; L < 4; ++L) {
        const _Float16* f2L = (L == 0 ? f2p0 : L == 1 ? f2p1 : L == 2 ? f2p2 : f2p3);
        const int Ww = WwT[L], Wp = WpT[L];
        const _Float16* f2b = f2L + (size_t)b * PBT[L]
                            + ((size_t)(Y0cS[L] + 5) * Wp + (X0cS[L] + 5)) * DCH;
        for (int rt = wave; rt < NTT[L]; rt += 4) {
            // A[m][k]: lane holds m=lane&15 (edge-clamped), k=(lane>>4)*8+j
            int m = min(rt * 16 + (lane & 15), MT[L] - 1);
            int my = (m * MAGT[L]) >> 21;
            int mx = m - my * Ww;
            const float4* ap = (const float4*)(f2b + (size_t)(my * Wp + mx) * DCH);
            f32x4 acc = {0.f, 0.f, 0.f, 0.f};
#pragma unroll
            for (int kk = 0; kk < 8; ++kk) {
                half8 av = __builtin_bit_cast(half8, ap[(lane >> 4) + 4 * kk]);
                acc = __builtin_amdgcn_mfma_f32_16x16x32_f16(av, bf[kk], acc, 0, 0, 0);
            }
            // D[m][n]: m=(lane>>4)*4+r (+tile base), n=lane&15
            int gr = rt * 16 + (lane >> 4) * 4;
#pragma unroll
            for (int r = 0; r < 4; ++r) G[(gr + r) * 17 + (lane & 15)] = acc[r];
        }
        __syncthreads();
        for (int idx = tid; idx < 1296; idx += 256) {
            int k = idx >> 4, x = idx & 15;
            int a = (k * 57) >> 9;            // k/9, exact for k<=80
            int c = k - 9 * a;
            int gx = lxS[L][x] + a, gy = lyS[L][x] + c;
            int m00 = gy * Ww + gx;
            float fx = fxS[L][x], fy = fyS[L][x];
            float t00 = G[m00 * 17 + x];
            float t01 = G[(m00 + 1) * 17 + x];
            float t10 = G[(m00 + Ww) * 17 + x];
            float t11 = G[(m00 + Ww + 1) * 17 + x];
            float v = ((1.f - fy) * ((1.f - fx) * t00 + fx * t01)
                     + fy * ((1.f - fx) * t10 + fx * t11)) * 0.0625f;
            sc[L * 1296 + k * 16 + x] = (_Float16)v;
        }
        __syncthreads();
    }
}

// ---------- unsort: scratch[rank[n]] -> out[b][ch][n], coalesced ----------
__global__ __launch_bounds__(256) void unsort_k(const _Float16* __restrict__ scratch,
                                                const int* __restrict__ rank,
                                                float* __restrict__ out) {
    int bid = blockIdx.x;                  // b(2) x ch(324) x seg(25)
    int seg = bid % 25;
    int ch = (bid / 25) % 324;
    int b = bid / (25 * 324);
    int nl = seg * 256 + threadIdx.x;
    int rk = rank[b * 6400 + nl];
    float v = (float)scratch[(size_t)(rk >> 4) * 5184 + ch * 16 + (rk & 15)];
    out[((size_t)b * 324 + ch) * 6400 + nl] = v;
}

extern "C" void kernel_launch(void* const* d_in, const int* in_sizes, int n_in,
                              void* d_out, int out_size, void* d_ws, size_t ws_size,
                              hipStream_t stream) {
    const float* fmap1 = (const float*)d_in[0];
    const float* fmap2 = (const float*)d_in[1];
    const float* coords = (const float*)d_in[2];
    float* out = (float*)d_out;
    char* ws = (char*)d_ws;

    _Float16* f1h  = (_Float16*)(ws);                  //  6,553,600
    _Float16* f2p0 = (_Float16*)(ws + 6553600);        //  8,294,400
    _Float16* f2p1 = (_Float16*)(ws + 14848000);       //  2,560,000
    _Float16* f2p2 = (_Float16*)(ws + 17408000);       //    921,600
    _Float16* f2p3 = (_Float16*)(ws + 18329600);       //    409,600
    unsigned int* hist   = (unsigned int*)(ws + 18739200);
    unsigned int* pstart = (unsigned int*)(ws + 18742400);
    unsigned int* cursor = (unsigned int*)(ws + 18745600);
    int* sortedIdxP = (int*)(ws + 18748800);           //   102,400 (25600 ints)
    int* rank       = (int*)(ws + 18851200);           //    51,200
    _Float16* scratch = (_Float16*)(ws + 18902400);    // 16,588,800 (total ~35.5 MB)

    // zero borders (interiors are overwritten) + slot sentinels
    hipMemsetAsync(f2p0, 0, 8294400, stream);
    hipMemsetAsync(f2p1, 0, 2560000, stream);
    hipMemsetAsync(f2p2, 0, 921600, stream);
    hipMemsetAsync(f2p3, 0, 409600, stream);
    hipMemsetAsync(sortedIdxP, 0xFF, 102400, stream);

    transpose_pad<<<dim3(400), dim3(256), 0, stream>>>(fmap1, f1h, 80, 0, 6400);
    transpose_pad<<<dim3(400), dim3(256), 0, stream>>>(fmap2, f2p0, 90, 5, 8100);
    pool2p<<<dim3(1600), dim3(256), 0, stream>>>(f2p0, f2p1, 40, 40, 90, 50,
                                                 90 * 90 * 128, 50 * 50 * 128, 409600);
    pool2p<<<dim3(400), dim3(256), 0, stream>>>(f2p1, f2p2, 20, 20, 50, 30,
                                                50 * 50 * 128, 30 * 30 * 128, 102400);
    pool2p<<<dim3(100), dim3(256), 0, stream>>>(f2p2, f2p3, 10, 10, 30, 20,
                                                30 * 30 * 128, 20 * 20 * 128, 25600);

    zero_hist<<<dim3(1), dim3(1024), 0, stream>>>(hist);
    hist_k<<<dim3(13), dim3(1024), 0, stream>>>(coords, hist);
    scan_k<<<dim3(1), dim3(1024), 0, stream>>>(hist, pstart, cursor);
    scatter_k<<<dim3(13), dim3(1024), 0, stream>>>(coords, cursor, sortedIdxP, rank);
    fill_k<<<dim3(1), dim3(1024), 0, stream>>>(hist, pstart, sortedIdxP);

    corr_mfma<<<dim3(MAXBLK), dim3(256), 0, stream>>>(f1h, f2p0, f2p1, f2p2, f2p3,
                                                      coords, sortedIdxP, scratch);
    unsort_k<<<dim3(16200), dim3(256), 0, stream>>>(scratch, rank, out);
}

// Round 8
// 106.255 us; speedup vs baseline: 1.5469x; 1.2551x over previous
//
#include <hip/hip_runtime.h>

// RAFT corr block: B=2, D=256, H=W=80, 4 levels, radius 4.
// avg_pool2(corr) over fmap2's spatial dims == corr with avg-pooled fmap2.
// R8: f2 pyramid in K-plane layout [b][k/32][H][W][32ch] so MFMA A-frag loads
// are coalesced (64B payload per pixel, contiguous along window rows);
// aux pipeline fused 18 -> 8 dispatches; single-block bucket sort kernel.

typedef _Float16 h2 __attribute__((ext_vector_type(2)));
typedef _Float16 half8 __attribute__((ext_vector_type(8)));
typedef float f32x4 __attribute__((ext_vector_type(4)));

#define HWDIM 80
#define DCH 256
#define NPIX 12800
#define NBUCKET 800

// ---------- fused transpose: f1 -> spatial-major f16; f2 -> K-plane padded ----------
__global__ __launch_bounds__(256) void transpose_all(const float* __restrict__ f1,
                                                     const float* __restrict__ f2,
                                                     _Float16* __restrict__ f1h,
                                                     _Float16* __restrict__ f2p0) {
    __shared__ float tile[256][33];
    int bid = blockIdx.x;
    bool isf1 = bid < 400;
    int lb = isf1 ? bid : bid - 400;
    const float* src = isf1 ? f1 : f2;
    int b = lb / 200;
    int s0 = (lb % 200) * 32;
    int t = threadIdx.x;
    const float* sb = src + (size_t)b * DCH * (HWDIM * HWDIM);
#pragma unroll 4
    for (int k = 0; k < 32; ++k) {
        int j = t + 256 * k;
        int c = j >> 5, s = j & 31;
        tile[c][s] = sb[(size_t)c * (HWDIM * HWDIM) + s0 + s];
    }
    __syncthreads();
    int p = t & 127;
    int srow = t >> 7;
    if (isf1) {
        _Float16* db = f1h + ((size_t)b * 6400 + s0) * DCH;
#pragma unroll 4
        for (int k = 0; k < 16; ++k) {
            int s = 2 * k + srow;
            h2 v;
            v[0] = (_Float16)tile[2 * p][s];
            v[1] = (_Float16)tile[2 * p + 1][s];
            *(h2*)(db + (size_t)s * DCH + 2 * p) = v;
        }
    } else {
#pragma unroll 4
        for (int k = 0; k < 16; ++k) {
            int s = 2 * k + srow;
            int spatial = s0 + s;
            int yy = spatial / 80;
            int xx = spatial - yy * 80;
            h2 v;
            v[0] = (_Float16)tile[2 * p][s];
            v[1] = (_Float16)tile[2 * p + 1][s];
            size_t off = (size_t)b * 2073600 + (size_t)(p >> 4) * 259200
                       + ((size_t)(yy + 5) * 90 + (xx + 5)) * 32 + ((2 * p) & 31);
            *(h2*)(f2p0 + off) = v;
        }
    }
}

// ---------- 2x2 pool in K-plane layout (level 0 -> 1) ----------
__global__ __launch_bounds__(256) void pool1(const _Float16* __restrict__ src,
                                             _Float16* __restrict__ dst) {
    int i = blockIdx.x * 256 + threadIdx.x;      // B*8*40*40*16 = 409600
    int c2 = i & 15;
    int r = i >> 4;
    int x = r % 40; r /= 40;
    int y = r % 40; r /= 40;
    int pl = r & 7;
    int b = r >> 3;
    const h2* s = (const h2*)src + ((size_t)b * 2073600 + (size_t)pl * 259200) / 2
                + ((size_t)(2 * y + 5) * 90 + (2 * x + 5)) * 16 + c2;
    h2 v00 = s[0], v01 = s[16], v10 = s[90 * 16], v11 = s[90 * 16 + 16];
    float r0 = ((float)v00[0] + (float)v01[0] + (float)v10[0] + (float)v11[0]) * 0.25f;
    float r1 = ((float)v00[1] + (float)v01[1] + (float)v10[1] + (float)v11[1]) * 0.25f;
    h2 o; o[0] = (_Float16)r0; o[1] = (_Float16)r1;
    *((h2*)dst + ((size_t)b * 640000 + (size_t)pl * 80000) / 2
      + ((size_t)(y + 5) * 50 + (x + 5)) * 16 + c2) = o;
}

// ---------- pools L2 (2x2 of L1) and L3 (4x4 of L1), fused ----------
__global__ __launch_bounds__(256) void pool23(const _Float16* __restrict__ l1,
                                              _Float16* __restrict__ l2,
                                              _Float16* __restrict__ l3) {
    int i = blockIdx.x * 256 + threadIdx.x;      // 102400 (L2) + 25600 (L3)
    if (i < 102400) {
        int c2 = i & 15;
        int r = i >> 4;
        int x = r % 20; r /= 20;
        int y = r % 20; r /= 20;
        int pl = r & 7;
        int b = r >> 3;
        const h2* s = (const h2*)l1 + ((size_t)b * 640000 + (size_t)pl * 80000) / 2
                    + ((size_t)(2 * y + 5) * 50 + (2 * x + 5)) * 16 + c2;
        h2 v00 = s[0], v01 = s[16], v10 = s[50 * 16], v11 = s[50 * 16 + 16];
        float r0 = ((float)v00[0] + (float)v01[0] + (float)v10[0] + (float)v11[0]) * 0.25f;
        float r1 = ((float)v00[1] + (float)v01[1] + (float)v10[1] + (float)v11[1]) * 0.25f;
        h2 o; o[0] = (_Float16)r0; o[1] = (_Float16)r1;
        *((h2*)l2 + ((size_t)b * 230400 + (size_t)pl * 28800) / 2
          + ((size_t)(y + 5) * 30 + (x + 5)) * 16 + c2) = o;
    } else {
        int j = i - 102400;
        int c2 = j & 15;
        int r = j >> 4;
        int x = r % 10; r /= 10;
        int y = r % 10; r /= 10;
        int pl = r & 7;
        int b = r >> 3;
        const h2* s = (const h2*)l1 + ((size_t)b * 640000 + (size_t)pl * 80000) / 2 + c2;
        float r0 = 0.f, r1 = 0.f;
#pragma unroll
        for (int dy = 0; dy < 4; ++dy)
#pragma unroll
            for (int dx = 0; dx < 4; ++dx) {
                h2 v = s[((size_t)(4 * y + dy + 5) * 50 + (4 * x + dx + 5)) * 16];
                r0 += (float)v[0];
                r1 += (float)v[1];
            }
        h2 o; o[0] = (_Float16)(r0 * 0.0625f); o[1] = (_Float16)(r1 * 0.0625f);
        *((h2*)l3 + ((size_t)b * 102400 + (size_t)pl * 12800) / 2
          + ((size_t)(y + 5) * 20 + (x + 5)) * 16 + c2) = o;
    }
}

// ---------- single-block bucket sort: hist+scan+scatter+fill in LDS ----------
static __device__ __forceinline__ int bucket_of(const float* coords, int n) {
    int b = n / 6400;
    int r = n - b * 6400;
    float cx = coords[(size_t)b * 12800 + r];
    float cy = coords[(size_t)b * 12800 + 6400 + r];
    int ix = min(max((int)floorf(cx), 0), 79);
    int iy = min(max((int)floorf(cy), 0), 79);
    return b * 400 + (iy >> 2) * 20 + (ix >> 2);
}

__global__ __launch_bounds__(1024) void bucket_k(const float* __restrict__ coords,
                                                 int* __restrict__ sortedIdxP,
                                                 int* __restrict__ rank) {
    __shared__ unsigned int histS[NBUCKET], scanS[1024], startS[NBUCKET], curS[NBUCKET];
    int t = threadIdx.x;
    if (t < NBUCKET) histS[t] = 0u;
    __syncthreads();
    int bkt[13];
#pragma unroll
    for (int i = 0; i < 13; ++i) {
        int n = i * 1024 + t;
        if (n < NPIX) {
            bkt[i] = bucket_of(coords, n);
            atomicAdd(&histS[bkt[i]], 1u);
        }
    }
    __syncthreads();
    scanS[t] = (t < NBUCKET) ? ((histS[t] + 15u) & ~15u) : 0u;
    __syncthreads();
    for (int d = 1; d < 1024; d <<= 1) {
        unsigned int v = (t >= d) ? scanS[t - d] : 0u;
        __syncthreads();
        scanS[t] += v;
        __syncthreads();
    }
    if (t < NBUCKET) {
        unsigned int e = t ? scanS[t - 1] : 0u;
        startS[t] = e;
        curS[t] = e;
    }
    __syncthreads();
#pragma unroll
    for (int i = 0; i < 13; ++i) {
        int n = i * 1024 + t;
        if (n < NPIX) {
            unsigned int pos = atomicAdd(&curS[bkt[i]], 1u);
            sortedIdxP[pos] = n;
            rank[n] = (int)pos;
        }
    }
    __syncthreads();
    if (t < NBUCKET) {
        unsigned int h = histS[t];
        if (h) {
            unsigned int pc = (h + 15u) & ~15u;
            unsigned int base = startS[t];
            int dup = sortedIdxP[base];
            for (unsigned int s = h; s < pc; ++s) sortedIdxP[base + s] = dup;
        }
    }
}

// ---------- main: per-bucket gather-GEMM via MFMA (K-plane A operand) ----------
// 512 threads = 8 waves. Block l: 16 slots of one bucket. Per level L:
// G[row,px] = sum_k F2[row][k]*F1[px][k] with mfma_f32_16x16x32_f16;
// A-frag loads hit contiguous 64B payloads (K-plane layout).
__global__ __launch_bounds__(512) void corr_mfma(
    const _Float16* __restrict__ f1h,
    const _Float16* __restrict__ f2p0, const _Float16* __restrict__ f2p1,
    const _Float16* __restrict__ f2p2, const _Float16* __restrict__ f2p3,
    const float* __restrict__ coords, const int* __restrict__ sortedIdxP,
    _Float16* __restrict__ scratch) {
    __shared__ float G[176 * 17];
    __shared__ float fxS[4][16], fyS[4][16];
    __shared__ int lxS[4][16], lyS[4][16];
    __shared__ int X0cS[4], Y0cS[4], bS;

    int pphys = blockIdx.x;
    int l = (pphys & 7) * 200 + (pphys >> 3);   // XCD swizzle, 1600 % 8 == 0
    int tid = threadIdx.x;
    if (sortedIdxP[l * 16] < 0) return;
    int lane = tid & 63;
    int wave = tid >> 6;

    // B fragments: f1 channels for the block's 16 pixels, all 8 k-steps.
    int npx = sortedIdxP[l * 16 + (lane & 15)];
    const float4* f1p = (const float4*)(f1h + (size_t)npx * DCH);
    half8 bf[8];
#pragma unroll
    for (int kk = 0; kk < 8; ++kk)
        bf[kk] = __builtin_bit_cast(half8, f1p[(lane >> 4) + 4 * kk]);

    if (tid < 64) {
        int px = tid & 15, Lt = tid >> 4;
        int n = sortedIdxP[l * 16 + px];
        int b = n / 6400;
        int r = n - b * 6400;
        float cx = coords[(size_t)b * 12800 + r];
        float cy = coords[(size_t)b * 12800 + 6400 + r];
        float ls = 1.0f / (float)(1 << Lt);
        float cxl = cx * ls, cyl = cy * ls;
        float fxf = floorf(cxl), fyf = floorf(cyl);
        int X0 = (int)fxf - 4, Y0 = (int)fyf - 4;
        int ix = min(max((int)floorf(cx), 0), 79);
        int iy = min(max((int)floorf(cy), 0), 79);
        int X0c = (((ix >> 2) * 4) >> Lt) - 4;
        int Y0c = (((iy >> 2) * 4) >> Lt) - 4;
        lxS[Lt][px] = min(max(X0 - X0c, 0), 3);
        lyS[Lt][px] = min(max(Y0 - Y0c, 0), 3);
        fxS[Lt][px] = cxl - fxf;
        fyS[Lt][px] = cyl - fyf;
        X0cS[Lt] = X0c;
        Y0cS[Lt] = Y0c;
        if (tid == 0) bS = sortedIdxP[l * 16] / 6400;
    }
    __syncthreads();
    int b = bS;
    _Float16* sc = scratch + (size_t)l * 5184;

    const int WwT[4]  = {13, 11, 10, 10};
    const int MT[4]   = {169, 121, 100, 100};
    const int NTT[4]  = {11, 8, 7, 7};
    const int MAGT[4] = {161320, 190652, 209716, 209716};  // >= ceil(2^21/Ww)
    const int WpT[4]  = {90, 50, 30, 20};
    const int PST[4]  = {259200, 80000, 28800, 12800};     // plane size, f16
    const int PBT[4]  = {2073600, 640000, 230400, 102400}; // batch size, f16

#pragma unroll
    for (int L = 0; L < 4; ++L) {
        const _Float16* f2L = (L == 0 ? f2p0 : L == 1 ? f2p1 : L == 2 ? f2p2 : f2p3);
        const int Ww = WwT[L], Wp = WpT[L];
        const _Float16* f2b = f2L + (size_t)b * PBT[L]
                            + ((size_t)(Y0cS[L] + 5) * Wp + (X0cS[L] + 5)) * 32;
        for (int rt = wave; rt < NTT[L]; rt += 8) {
            // A[m][k]: lane holds m=lane&15 (edge-clamped), k=(lane>>4)*8+j;
            // plane kk supplies this tile's 32-channel k-step.
            int m = min(rt * 16 + (lane & 15), MT[L] - 1);
            int my = (m * MAGT[L]) >> 21;
            int mx = m - my * Ww;
            const float4* ap = (const float4*)(f2b + (size_t)(my * Wp + mx) * 32)
                             + (lane >> 4);
            f32x4 acc = {0.f, 0.f, 0.f, 0.f};
#pragma unroll
            for (int kk = 0; kk < 8; ++kk) {
                half8 av = __builtin_bit_cast(half8, ap[kk * (PST[L] / 8)]);
                acc = __builtin_amdgcn_mfma_f32_16x16x32_f16(av, bf[kk], acc, 0, 0, 0);
            }
            int gr = rt * 16 + (lane >> 4) * 4;
#pragma unroll
            for (int r = 0; r < 4; ++r) G[(gr + r) * 17 + (lane & 15)] = acc[r];
        }
        __syncthreads();
        for (int idx = tid; idx < 1296; idx += 512) {
            int k = idx >> 4, x = idx & 15;
            int a = (k * 57) >> 9;            // k/9, exact for k<=80
            int c = k - 9 * a;
            int gx = lxS[L][x] + a, gy = lyS[L][x] + c;
            int m00 = gy * Ww + gx;
            float fx = fxS[L][x], fy = fyS[L][x];
            float t00 = G[m00 * 17 + x];
            float t01 = G[(m00 + 1) * 17 + x];
            float t10 = G[(m00 + Ww) * 17 + x];
            float t11 = G[(m00 + Ww + 1) * 17 + x];
            float v = ((1.f - fy) * ((1.f - fx) * t00 + fx * t01)
                     + fy * ((1.f - fx) * t10 + fx * t11)) * 0.0625f;
            sc[L * 1296 + k * 16 + x] = (_Float16)v;
        }
        __syncthreads();
    }
}

// ---------- unsort: scratch[rank[n]] -> out[b][ch][n], float4 stores ----------
__global__ __launch_bounds__(256) void unsort4(const _Float16* __restrict__ scratch,
                                               const int* __restrict__ rank,
                                               float* __restrict__ out) {
    int u = blockIdx.x * 256 + threadIdx.x;   // 2*324*1600 = 1,036,800
    int q = u % 1600;
    int ch = (u / 1600) % 324;
    int b = u / (1600 * 324);
    int nl = q * 4;
    int4 rk = *(const int4*)(rank + b * 6400 + nl);
    float4 v;
    v.x = (float)scratch[(size_t)(rk.x >> 4) * 5184 + ch * 16 + (rk.x & 15)];
    v.y = (float)scratch[(size_t)(rk.y >> 4) * 5184 + ch * 16 + (rk.y & 15)];
    v.z = (float)scratch[(size_t)(rk.z >> 4) * 5184 + ch * 16 + (rk.z & 15)];
    v.w = (float)scratch[(size_t)(rk.w >> 4) * 5184 + ch * 16 + (rk.w & 15)];
    *(float4*)(out + ((size_t)b * 324 + ch) * 6400 + nl) = v;
}

extern "C" void kernel_launch(void* const* d_in, const int* in_sizes, int n_in,
                              void* d_out, int out_size, void* d_ws, size_t ws_size,
                              hipStream_t stream) {
    const float* fmap1 = (const float*)d_in[0];
    const float* fmap2 = (const float*)d_in[1];
    const float* coords = (const float*)d_in[2];
    float* out = (float*)d_out;
    char* ws = (char*)d_ws;

    _Float16* f1h  = (_Float16*)(ws);                  //  6,553,600
    _Float16* f2p0 = (_Float16*)(ws + 6553600);        //  8,294,400 (K-plane, pad 5)
    _Float16* f2p1 = (_Float16*)(ws + 14848000);       //  2,560,000
    _Float16* f2p2 = (_Float16*)(ws + 17408000);       //    921,600
    _Float16* f2p3 = (_Float16*)(ws + 18329600);       //    409,600
    int* sortedIdxP = (int*)(ws + 18739200);           //    102,400 (25600 ints)
    int* rank       = (int*)(ws + 18841600);           //     51,200
    _Float16* scratch = (_Float16*)(ws + 18892800);    // 16,588,800 (total ~35.5 MB)

    // zero all pyramid borders in one shot (buffers are contiguous); sentinels
    hipMemsetAsync(f2p0, 0, 12185600, stream);
    hipMemsetAsync(sortedIdxP, 0xFF, 102400, stream);

    transpose_all<<<dim3(800), dim3(256), 0, stream>>>(fmap1, fmap2, f1h, f2p0);
    pool1<<<dim3(1600), dim3(256), 0, stream>>>(f2p0, f2p1);
    pool23<<<dim3(500), dim3(256), 0, stream>>>(f2p1, f2p2, f2p3);
    bucket_k<<<dim3(1), dim3(1024), 0, stream>>>(coords, sortedIdxP, rank);
    corr_mfma<<<dim3(1600), dim3(512), 0, stream>>>(f1h, f2p0, f2p1, f2p2, f2p3,
                                                    coords, sortedIdxP, scratch);
    unsort4<<<dim3(4050), dim3(256), 0, stream>>>(scratch, rank, out);
}

// Round 10
// 104.311 us; speedup vs baseline: 1.5757x; 1.0186x over previous
//
#include <hip/hip_runtime.h>

// RAFT corr block: B=2, D=256, H=W=80, 4 levels, radius 4.
// avg_pool2(corr) over fmap2's spatial dims == corr with avg-pooled fmap2.
// R10: R9 (flattened 33-tile MFMA, 2 barriers) + epilogue magic-div fix
// (k2/81 magic 809 -> 810; 809 failed at k2=81/162/243).

typedef _Float16 h2 __attribute__((ext_vector_type(2)));
typedef _Float16 half8 __attribute__((ext_vector_type(8)));
typedef float f32x4 __attribute__((ext_vector_type(4)));

#define HWDIM 80
#define DCH 256
#define NPIX 12800
#define NBUCKET 800

// ---------- fused transpose: f1 -> spatial-major f16; f2 -> K-plane padded ----------
__global__ __launch_bounds__(256) void transpose_all(const float* __restrict__ f1,
                                                     const float* __restrict__ f2,
                                                     _Float16* __restrict__ f1h,
                                                     _Float16* __restrict__ f2p0) {
    __shared__ float tile[256][33];
    int bid = blockIdx.x;
    bool isf1 = bid < 400;
    int lb = isf1 ? bid : bid - 400;
    const float* src = isf1 ? f1 : f2;
    int b = lb / 200;
    int s0 = (lb % 200) * 32;
    int t = threadIdx.x;
    const float* sb = src + (size_t)b * DCH * (HWDIM * HWDIM);
#pragma unroll 4
    for (int k = 0; k < 32; ++k) {
        int j = t + 256 * k;
        int c = j >> 5, s = j & 31;
        tile[c][s] = sb[(size_t)c * (HWDIM * HWDIM) + s0 + s];
    }
    __syncthreads();
    int p = t & 127;
    int srow = t >> 7;
    if (isf1) {
        _Float16* db = f1h + ((size_t)b * 6400 + s0) * DCH;
#pragma unroll 4
        for (int k = 0; k < 16; ++k) {
            int s = 2 * k + srow;
            h2 v;
            v[0] = (_Float16)tile[2 * p][s];
            v[1] = (_Float16)tile[2 * p + 1][s];
            *(h2*)(db + (size_t)s * DCH + 2 * p) = v;
        }
    } else {
#pragma unroll 4
        for (int k = 0; k < 16; ++k) {
            int s = 2 * k + srow;
            int spatial = s0 + s;
            int yy = spatial / 80;
            int xx = spatial - yy * 80;
            h2 v;
            v[0] = (_Float16)tile[2 * p][s];
            v[1] = (_Float16)tile[2 * p + 1][s];
            size_t off = (size_t)b * 2073600 + (size_t)(p >> 4) * 259200
                       + ((size_t)(yy + 5) * 90 + (xx + 5)) * 32 + ((2 * p) & 31);
            *(h2*)(f2p0 + off) = v;
        }
    }
}

// ---------- 2x2 pool in K-plane layout (level 0 -> 1) ----------
__global__ __launch_bounds__(256) void pool1(const _Float16* __restrict__ src,
                                             _Float16* __restrict__ dst) {
    int i = blockIdx.x * 256 + threadIdx.x;      // B*8*40*40*16 = 409600
    int c2 = i & 15;
    int r = i >> 4;
    int x = r % 40; r /= 40;
    int y = r % 40; r /= 40;
    int pl = r & 7;
    int b = r >> 3;
    const h2* s = (const h2*)src + ((size_t)b * 2073600 + (size_t)pl * 259200) / 2
                + ((size_t)(2 * y + 5) * 90 + (2 * x + 5)) * 16 + c2;
    h2 v00 = s[0], v01 = s[16], v10 = s[90 * 16], v11 = s[90 * 16 + 16];
    float r0 = ((float)v00[0] + (float)v01[0] + (float)v10[0] + (float)v11[0]) * 0.25f;
    float r1 = ((float)v00[1] + (float)v01[1] + (float)v10[1] + (float)v11[1]) * 0.25f;
    h2 o; o[0] = (_Float16)r0; o[1] = (_Float16)r1;
    *((h2*)dst + ((size_t)b * 640000 + (size_t)pl * 80000) / 2
      + ((size_t)(y + 5) * 50 + (x + 5)) * 16 + c2) = o;
}

// ---------- pools L2 (2x2 of L1) and L3 (4x4 of L1), fused ----------
__global__ __launch_bounds__(256) void pool23(const _Float16* __restrict__ l1,
                                              _Float16* __restrict__ l2,
                                              _Float16* __restrict__ l3) {
    int i = blockIdx.x * 256 + threadIdx.x;      // 102400 (L2) + 25600 (L3)
    if (i < 102400) {
        int c2 = i & 15;
        int r = i >> 4;
        int x = r % 20; r /= 20;
        int y = r % 20; r /= 20;
        int pl = r & 7;
        int b = r >> 3;
        const h2* s = (const h2*)l1 + ((size_t)b * 640000 + (size_t)pl * 80000) / 2
                    + ((size_t)(2 * y + 5) * 50 + (2 * x + 5)) * 16 + c2;
        h2 v00 = s[0], v01 = s[16], v10 = s[50 * 16], v11 = s[50 * 16 + 16];
        float r0 = ((float)v00[0] + (float)v01[0] + (float)v10[0] + (float)v11[0]) * 0.25f;
        float r1 = ((float)v00[1] + (float)v01[1] + (float)v10[1] + (float)v11[1]) * 0.25f;
        h2 o; o[0] = (_Float16)r0; o[1] = (_Float16)r1;
        *((h2*)l2 + ((size_t)b * 230400 + (size_t)pl * 28800) / 2
          + ((size_t)(y + 5) * 30 + (x + 5)) * 16 + c2) = o;
    } else {
        int j = i - 102400;
        int c2 = j & 15;
        int r = j >> 4;
        int x = r % 10; r /= 10;
        int y = r % 10; r /= 10;
        int pl = r & 7;
        int b = r >> 3;
        const h2* s = (const h2*)l1 + ((size_t)b * 640000 + (size_t)pl * 80000) / 2 + c2;
        float r0 = 0.f, r1 = 0.f;
#pragma unroll
        for (int dy = 0; dy < 4; ++dy)
#pragma unroll
            for (int dx = 0; dx < 4; ++dx) {
                h2 v = s[((size_t)(4 * y + dy + 5) * 50 + (4 * x + dx + 5)) * 16];
                r0 += (float)v[0];
                r1 += (float)v[1];
            }
        h2 o; o[0] = (_Float16)(r0 * 0.0625f); o[1] = (_Float16)(r1 * 0.0625f);
        *((h2*)l3 + ((size_t)b * 102400 + (size_t)pl * 12800) / 2
          + ((size_t)(y + 5) * 20 + (x + 5)) * 16 + c2) = o;
    }
}

// ---------- single-block bucket sort: hist + shfl-scan + scatter + fill ----------
static __device__ __forceinline__ int bucket_of(const float* coords, int n) {
    int b = n / 6400;
    int r = n - b * 6400;
    float cx = coords[(size_t)b * 12800 + r];
    float cy = coords[(size_t)b * 12800 + 6400 + r];
    int ix = min(max((int)floorf(cx), 0), 79);
    int iy = min(max((int)floorf(cy), 0), 79);
    return b * 400 + (iy >> 2) * 20 + (ix >> 2);
}

__global__ __launch_bounds__(1024) void bucket_k(const float* __restrict__ coords,
                                                 int* __restrict__ sortedIdxP,
                                                 int* __restrict__ rank) {
    __shared__ unsigned int histS[NBUCKET], startS[NBUCKET], curS[NBUCKET];
    __shared__ unsigned int waveSum[16];
    int t = threadIdx.x;
    if (t < NBUCKET) histS[t] = 0u;
    __syncthreads();
    int bkt[13];
#pragma unroll
    for (int i = 0; i < 13; ++i) {
        int n = i * 1024 + t;
        if (n < NPIX) {
            bkt[i] = bucket_of(coords, n);
            atomicAdd(&histS[bkt[i]], 1u);
        }
    }
    __syncthreads();
    // inclusive scan of ceil16(hist) over 1024 slots: per-wave shfl + wave offsets
    unsigned int v = (t < NBUCKET) ? ((histS[t] + 15u) & ~15u) : 0u;
    unsigned int x = v;
#pragma unroll
    for (int d = 1; d < 64; d <<= 1) {
        unsigned int y = __shfl_up(x, d);
        if ((t & 63) >= d) x += y;
    }
    if ((t & 63) == 63) waveSum[t >> 6] = x;
    __syncthreads();
    if (t < 16) {
        unsigned int w = waveSum[t];
#pragma unroll
        for (int d = 1; d < 16; d <<= 1) {
            unsigned int y = __shfl_up(w, d);
            if (t >= d) w += y;
        }
        waveSum[t] = w;
    }
    __syncthreads();
    unsigned int incl = x + ((t >> 6) ? waveSum[(t >> 6) - 1] : 0u);
    if (t < NBUCKET) {
        unsigned int e = incl - v;           // exclusive
        startS[t] = e;
        curS[t] = e;
    }
    __syncthreads();
#pragma unroll
    for (int i = 0; i < 13; ++i) {
        int n = i * 1024 + t;
        if (n < NPIX) {
            unsigned int pos = atomicAdd(&curS[bkt[i]], 1u);
            sortedIdxP[pos] = n;
            rank[n] = (int)pos;
        }
    }
    __syncthreads();
    if (t < NBUCKET) {
        unsigned int h = histS[t];
        if (h) {
            unsigned int pc = (h + 15u) & ~15u;
            unsigned int base = startS[t];
            int dup = sortedIdxP[base];
            for (unsigned int s = h; s < pc; ++s) sortedIdxP[base + s] = dup;
        }
    }
}

// ---------- main: per-bucket gather-GEMM, all 33 tiles flattened ----------
// 512 threads = 8 waves. Tile tt (compile-time) -> level L, row-tile rt.
// Wave-uniform ownership; single G buffer (4 level segments); 2 barriers.
__global__ __launch_bounds__(512, 4) void corr_mfma(
    const _Float16* __restrict__ f1h,
    const _Float16* __restrict__ f2p0, const _Float16* __restrict__ f2p1,
    const _Float16* __restrict__ f2p2, const _Float16* __restrict__ f2p3,
    const float* __restrict__ coords, const int* __restrict__ sortedIdxP,
    _Float16* __restrict__ scratch) {
    __shared__ float G[528 * 17];          // 176+128+112+112 rows, 35.9 KB
    __shared__ float fxS[4][16], fyS[4][16];
    __shared__ int lxS[4][16], lyS[4][16];
    __shared__ int X0cS[4], Y0cS[4], bS;

    int pphys = blockIdx.x;
    int l = (pphys & 7) * 200 + (pphys >> 3);   // XCD swizzle, 1600 % 8 == 0
    int tid = threadIdx.x;
    if (sortedIdxP[l * 16] < 0) return;
    int lane = tid & 63;
    int wave = tid >> 6;

    // B fragments: f1 channels for the block's 16 pixels, all 8 k-steps.
    int npx = sortedIdxP[l * 16 + (lane & 15)];
    const float4* f1p = (const float4*)(f1h + (size_t)npx * DCH);
    half8 bf[8];
#pragma unroll
    for (int kk = 0; kk < 8; ++kk)
        bf[kk] = __builtin_bit_cast(half8, f1p[(lane >> 4) + 4 * kk]);

    if (tid < 64) {
        int px = tid & 15, Lt = tid >> 4;
        int n = sortedIdxP[l * 16 + px];
        int b = n / 6400;
        int r = n - b * 6400;
        float cx = coords[(size_t)b * 12800 + r];
        float cy = coords[(size_t)b * 12800 + 6400 + r];
        float ls = 1.0f / (float)(1 << Lt);
        float cxl = cx * ls, cyl = cy * ls;
        float fxf = floorf(cxl), fyf = floorf(cyl);
        int X0 = (int)fxf - 4, Y0 = (int)fyf - 4;
        int ix = min(max((int)floorf(cx), 0), 79);
        int iy = min(max((int)floorf(cy), 0), 79);
        int X0c = (((ix >> 2) * 4) >> Lt) - 4;
        int Y0c = (((iy >> 2) * 4) >> Lt) - 4;
        lxS[Lt][px] = min(max(X0 - X0c, 0), 3);
        lyS[Lt][px] = min(max(Y0 - Y0c, 0), 3);
        fxS[Lt][px] = cxl - fxf;
        fyS[Lt][px] = cyl - fyf;
        X0cS[Lt] = X0c;
        Y0cS[Lt] = Y0c;
        if (tid == 0) bS = sortedIdxP[l * 16] / 6400;
    }
    __syncthreads();
    int b = bS;
    _Float16* sc = scratch + (size_t)l * 5184;

    // tiles: L0 rt 0..10 | L1 rt 0..7 | L2 rt 0..6 | L3 rt 0..6
#pragma unroll
    for (int tt = 0; tt < 33; ++tt) {
        const int L  = tt < 11 ? 0 : tt < 19 ? 1 : tt < 26 ? 2 : 3;
        const int rt = tt - (L == 0 ? 0 : L == 1 ? 11 : L == 2 ? 19 : 26);
        const int Ww = L == 0 ? 13 : L == 1 ? 11 : 10;
        const int MT = L == 0 ? 169 : L == 1 ? 121 : 100;
        const int MAG = L == 0 ? 161320 : L == 1 ? 190652 : 209716;
        const int Wp = L == 0 ? 90 : L == 1 ? 50 : L == 2 ? 30 : 20;
        const int PS = L == 0 ? 259200 : L == 1 ? 80000 : L == 2 ? 28800 : 12800;
        const int PB = L == 0 ? 2073600 : L == 1 ? 640000 : L == 2 ? 230400 : 102400;
        const int GO = L == 0 ? 0 : L == 1 ? 176 : L == 2 ? 304 : 416;
        // ownership: wave w takes tt with tt%8==w, except tile 32 -> wave 7
        if (tt == 32 ? (wave != 7) : ((tt & 7) != wave)) continue;
        const _Float16* f2L = (L == 0 ? f2p0 : L == 1 ? f2p1 : L == 2 ? f2p2 : f2p3);
        const _Float16* f2b = f2L + (size_t)b * PB
                            + ((size_t)(Y0cS[L] + 5) * Wp + (X0cS[L] + 5)) * 32;
        int m = min(rt * 16 + (lane & 15), MT - 1);
        int my = (m * MAG) >> 21;
        int mx = m - my * Ww;
        const float4* ap = (const float4*)(f2b + (size_t)(my * Wp + mx) * 32)
                         + (lane >> 4);
        f32x4 acc = {0.f, 0.f, 0.f, 0.f};
#pragma unroll
        for (int kk = 0; kk < 8; ++kk) {
            half8 av = __builtin_bit_cast(half8, ap[kk * (PS / 8)]);
            acc = __builtin_amdgcn_mfma_f32_16x16x32_f16(av, bf[kk], acc, 0, 0, 0);
        }
        int gr = GO + rt * 16 + (lane >> 4) * 4;
#pragma unroll
        for (int r = 0; r < 4; ++r) G[(gr + r) * 17 + (lane & 15)] = acc[r];
    }
    __syncthreads();

    // epilogue: 4 levels x 81 k x 16 slots
    for (int idx = tid; idx < 5184; idx += 512) {
        int k2 = idx >> 4, x = idx & 15;
        int Le = (k2 * 810) >> 16;            // k2/81, exact for k2<324
        int k = k2 - Le * 81;
        int Ww = Le == 0 ? 13 : Le == 1 ? 11 : 10;
        int GO = Le == 0 ? 0 : Le == 1 ? 176 : Le == 2 ? 304 : 416;
        int a = (k * 57) >> 9;                // k/9, exact for k<=80
        int c = k - 9 * a;
        int gx = lxS[Le][x] + a, gy = lyS[Le][x] + c;
        int m00 = GO + gy * Ww + gx;
        float fx = fxS[Le][x], fy = fyS[Le][x];
        float t00 = G[m00 * 17 + x];
        float t01 = G[(m00 + 1) * 17 + x];
        float t10 = G[(m00 + Ww) * 17 + x];
        float t11 = G[(m00 + Ww + 1) * 17 + x];
        float v = ((1.f - fy) * ((1.f - fx) * t00 + fx * t01)
                 + fy * ((1.f - fx) * t10 + fx * t11)) * 0.0625f;
        sc[idx] = (_Float16)v;
    }
}

// ---------- unsort: scratch[rank[n]] -> out[b][ch][n], float4 stores ----------
__global__ __launch_bounds__(256) void unsort4(const _Float16* __restrict__ scratch,
                                               const int* __restrict__ rank,
                                               float* __restrict__ out) {
    int u = blockIdx.x * 256 + threadIdx.x;   // 2*324*1600 = 1,036,800
    int q = u % 1600;
    int ch = (u / 1600) % 324;
    int b = u / (1600 * 324);
    int nl = q * 4;
    int4 rk = *(const int4*)(rank + b * 6400 + nl);
    float4 v;
    v.x = (float)scratch[(size_t)(rk.x >> 4) * 5184 + ch * 16 + (rk.x & 15)];
    v.y = (float)scratch[(size_t)(rk.y >> 4) * 5184 + ch * 16 + (rk.y & 15)];
    v.z = (float)scratch[(size_t)(rk.z >> 4) * 5184 + ch * 16 + (rk.z & 15)];
    v.w = (float)scratch[(size_t)(rk.w >> 4) * 5184 + ch * 16 + (rk.w & 15)];
    *(float4*)(out + ((size_t)b * 324 + ch) * 6400 + nl) = v;
}

extern "C" void kernel_launch(void* const* d_in, const int* in_sizes, int n_in,
                              void* d_out, int out_size, void* d_ws, size_t ws_size,
                              hipStream_t stream) {
    const float* fmap1 = (const float*)d_in[0];
    const float* fmap2 = (const float*)d_in[1];
    const float* coords = (const float*)d_in[2];
    float* out = (float*)d_out;
    char* ws = (char*)d_ws;

    _Float16* f1h  = (_Float16*)(ws);                  //  6,553,600
    _Float16* f2p0 = (_Float16*)(ws + 6553600);        //  8,294,400 (K-plane, pad 5)
    _Float16* f2p1 = (_Float16*)(ws + 14848000);       //  2,560,000
    _Float16* f2p2 = (_Float16*)(ws + 17408000);       //    921,600
    _Float16* f2p3 = (_Float16*)(ws + 18329600);       //    409,600
    int* sortedIdxP = (int*)(ws + 18739200);           //    102,400 (25600 ints)
    int* rank       = (int*)(ws + 18841600);           //     51,200
    _Float16* scratch = (_Float16*)(ws + 18892800);    // 16,588,800 (total ~35.5 MB)

    // zero all pyramid borders in one shot (buffers contiguous); slot sentinels
    hipMemsetAsync(f2p0, 0, 12185600, stream);
    hipMemsetAsync(sortedIdxP, 0xFF, 102400, stream);

    transpose_all<<<dim3(800), dim3(256), 0, stream>>>(fmap1, fmap2, f1h, f2p0);
    pool1<<<dim3(1600), dim3(256), 0, stream>>>(f2p0, f2p1);
    pool23<<<dim3(500), dim3(256), 0, stream>>>(f2p1, f2p2, f2p3);
    bucket_k<<<dim3(1), dim3(1024), 0, stream>>>(coords, sortedIdxP, rank);
    corr_mfma<<<dim3(1600), dim3(512), 0, stream>>>(f1h, f2p0, f2p1, f2p2, f2p3,
                                                    coords, sortedIdxP, scratch);
    unsort4<<<dim3(4050), dim3(256), 0, stream>>>(scratch, rank, out);
}

// Round 11
// 97.899 us; speedup vs baseline: 1.6789x; 1.0655x over previous
//
#include <hip/hip_runtime.h>

// RAFT corr block: B=2, D=256, H=W=80, 4 levels, radius 4.
// avg_pool2(corr) over fmap2's spatial dims == corr with avg-pooled fmap2.
// R11: corr_mfma — f1 block staged in LDS (kills 8x redundant gather +
// bf rematerialization), per-wave CONTIGUOUS compile-time tile ranges
// (straight-line code -> compiler can pipeline across tiles).
// Aux: pools fused to one kernel; bucket_k writes its own sentinels.

typedef _Float16 h2 __attribute__((ext_vector_type(2)));
typedef _Float16 half8 __attribute__((ext_vector_type(8)));
typedef float f32x4 __attribute__((ext_vector_type(4)));

#define HWDIM 80
#define DCH 256
#define NPIX 12800
#define NBUCKET 800

// ---------- fused transpose: f1 -> spatial-major f16; f2 -> K-plane padded ----------
__global__ __launch_bounds__(256) void transpose_all(const float* __restrict__ f1,
                                                     const float* __restrict__ f2,
                                                     _Float16* __restrict__ f1h,
                                                     _Float16* __restrict__ f2p0) {
    __shared__ float tile[256][33];
    int bid = blockIdx.x;
    bool isf1 = bid < 400;
    int lb = isf1 ? bid : bid - 400;
    const float* src = isf1 ? f1 : f2;
    int b = lb / 200;
    int s0 = (lb % 200) * 32;
    int t = threadIdx.x;
    const float* sb = src + (size_t)b * DCH * (HWDIM * HWDIM);
#pragma unroll 4
    for (int k = 0; k < 32; ++k) {
        int j = t + 256 * k;
        int c = j >> 5, s = j & 31;
        tile[c][s] = sb[(size_t)c * (HWDIM * HWDIM) + s0 + s];
    }
    __syncthreads();
    int p = t & 127;
    int srow = t >> 7;
    if (isf1) {
        _Float16* db = f1h + ((size_t)b * 6400 + s0) * DCH;
#pragma unroll 4
        for (int k = 0; k < 16; ++k) {
            int s = 2 * k + srow;
            h2 v;
            v[0] = (_Float16)tile[2 * p][s];
            v[1] = (_Float16)tile[2 * p + 1][s];
            *(h2*)(db + (size_t)s * DCH + 2 * p) = v;
        }
    } else {
#pragma unroll 4
        for (int k = 0; k < 16; ++k) {
            int s = 2 * k + srow;
            int spatial = s0 + s;
            int yy = spatial / 80;
            int xx = spatial - yy * 80;
            h2 v;
            v[0] = (_Float16)tile[2 * p][s];
            v[1] = (_Float16)tile[2 * p + 1][s];
            size_t off = (size_t)b * 2073600 + (size_t)(p >> 4) * 259200
                       + ((size_t)(yy + 5) * 90 + (xx + 5)) * 32 + ((2 * p) & 31);
            *(h2*)(f2p0 + off) = v;
        }
    }
}

// ---------- all pools from L0 directly (one kernel): L1 2x2, L2 4x4, L3 8x8 ----------
__global__ __launch_bounds__(256) void pools(const _Float16* __restrict__ l0,
                                             _Float16* __restrict__ l1,
                                             _Float16* __restrict__ l2,
                                             _Float16* __restrict__ l3) {
    int i = blockIdx.x * 256 + threadIdx.x;      // 409600 + 102400 + 25600 = 537600
    if (i < 409600) {
        int c2 = i & 15;
        int r = i >> 4;
        int x = r % 40; r /= 40;
        int y = r % 40; r /= 40;
        int pl = r & 7;
        int b = r >> 3;
        const h2* s = (const h2*)l0 + (size_t)b * 1036800 + (size_t)pl * 129600
                    + ((size_t)(2 * y + 5) * 90 + (2 * x + 5)) * 16 + c2;
        h2 v00 = s[0], v01 = s[16], v10 = s[90 * 16], v11 = s[90 * 16 + 16];
        float r0 = ((float)v00[0] + (float)v01[0] + (float)v10[0] + (float)v11[0]) * 0.25f;
        float r1 = ((float)v00[1] + (float)v01[1] + (float)v10[1] + (float)v11[1]) * 0.25f;
        h2 o; o[0] = (_Float16)r0; o[1] = (_Float16)r1;
        *((h2*)l1 + (size_t)b * 320000 + (size_t)pl * 40000
          + ((size_t)(y + 5) * 50 + (x + 5)) * 16 + c2) = o;
    } else if (i < 512000) {
        int j = i - 409600;
        int c2 = j & 15;
        int r = j >> 4;
        int x = r % 20; r /= 20;
        int y = r % 20; r /= 20;
        int pl = r & 7;
        int b = r >> 3;
        const h2* s = (const h2*)l0 + (size_t)b * 1036800 + (size_t)pl * 129600 + c2;
        float r0 = 0.f, r1 = 0.f;
#pragma unroll
        for (int dy = 0; dy < 4; ++dy)
#pragma unroll
            for (int dx = 0; dx < 4; ++dx) {
                h2 v = s[((size_t)(4 * y + dy + 5) * 90 + (4 * x + dx + 5)) * 16];
                r0 += (float)v[0];
                r1 += (float)v[1];
            }
        h2 o; o[0] = (_Float16)(r0 * 0.0625f); o[1] = (_Float16)(r1 * 0.0625f);
        *((h2*)l2 + (size_t)b * 115200 + (size_t)pl * 14400
          + ((size_t)(y + 5) * 30 + (x + 5)) * 16 + c2) = o;
    } else {
        int j = i - 512000;
        int c2 = j & 15;
        int r = j >> 4;
        int x = r % 10; r /= 10;
        int y = r % 10; r /= 10;
        int pl = r & 7;
        int b = r >> 3;
        const h2* s = (const h2*)l0 + (size_t)b * 1036800 + (size_t)pl * 129600 + c2;
        float r0 = 0.f, r1 = 0.f;
#pragma unroll
        for (int dy = 0; dy < 8; ++dy)
#pragma unroll
            for (int dx = 0; dx < 8; ++dx) {
                h2 v = s[((size_t)(8 * y + dy + 5) * 90 + (8 * x + dx + 5)) * 16];
                r0 += (float)v[0];
                r1 += (float)v[1];
            }
        h2 o; o[0] = (_Float16)(r0 * 0.015625f); o[1] = (_Float16)(r1 * 0.015625f);
        *((h2*)l3 + (size_t)b * 51200 + (size_t)pl * 6400
          + ((size_t)(y + 5) * 20 + (x + 5)) * 16 + c2) = o;
    }
}

// ---------- single-block bucket sort: hist + shfl-scan + scatter + fill + sentinel ----------
static __device__ __forceinline__ int bucket_of(const float* coords, int n) {
    int b = n / 6400;
    int r = n - b * 6400;
    float cx = coords[(size_t)b * 12800 + r];
    float cy = coords[(size_t)b * 12800 + 6400 + r];
    int ix = min(max((int)floorf(cx), 0), 79);
    int iy = min(max((int)floorf(cy), 0), 79);
    return b * 400 + (iy >> 2) * 20 + (ix >> 2);
}

__global__ __launch_bounds__(1024) void bucket_k(const float* __restrict__ coords,
                                                 int* __restrict__ sortedIdxP,
                                                 int* __restrict__ rank) {
    __shared__ unsigned int histS[NBUCKET], startS[NBUCKET], curS[NBUCKET];
    __shared__ unsigned int waveSum[16];
    __shared__ unsigned int totalS;
    int t = threadIdx.x;
    if (t < NBUCKET) histS[t] = 0u;
    __syncthreads();
    int bkt[13];
#pragma unroll
    for (int i = 0; i < 13; ++i) {
        int n = i * 1024 + t;
        if (n < NPIX) {
            bkt[i] = bucket_of(coords, n);
            atomicAdd(&histS[bkt[i]], 1u);
        }
    }
    __syncthreads();
    unsigned int v = (t < NBUCKET) ? ((histS[t] + 15u) & ~15u) : 0u;
    unsigned int x = v;
#pragma unroll
    for (int d = 1; d < 64; d <<= 1) {
        unsigned int y = __shfl_up(x, d);
        if ((t & 63) >= d) x += y;
    }
    if ((t & 63) == 63) waveSum[t >> 6] = x;
    __syncthreads();
    if (t < 16) {
        unsigned int w = waveSum[t];
#pragma unroll
        for (int d = 1; d < 16; d <<= 1) {
            unsigned int y = __shfl_up(w, d);
            if (t >= d) w += y;
        }
        waveSum[t] = w;
    }
    __syncthreads();
    unsigned int incl = x + ((t >> 6) ? waveSum[(t >> 6) - 1] : 0u);
    if (t < NBUCKET) {
        unsigned int e = incl - v;
        startS[t] = e;
        curS[t] = e;
        if (t == NBUCKET - 1) totalS = incl;
    }
    __syncthreads();
#pragma unroll
    for (int i = 0; i < 13; ++i) {
        int n = i * 1024 + t;
        if (n < NPIX) {
            unsigned int pos = atomicAdd(&curS[bkt[i]], 1u);
            sortedIdxP[pos] = n;
            rank[n] = (int)pos;
        }
    }
    __syncthreads();
    if (t < NBUCKET) {
        unsigned int h = histS[t];
        if (h) {
            unsigned int pc = (h + 15u) & ~15u;
            unsigned int base = startS[t];
            int dup = sortedIdxP[base];
            for (unsigned int s = h; s < pc; ++s) sortedIdxP[base + s] = dup;
        }
    }
    // sentinels for unused padded slots (replaces a 0xFF memset dispatch)
    for (unsigned int s = totalS + t; s < 25600u; s += 1024u) sortedIdxP[s] = -1;
}

// ---------- per-wave straight-line tile runner (compile-time range) ----------
template <int TB, int TE>
static __device__ __forceinline__ void run_tiles(
    int lane, int b,
    const _Float16* __restrict__ f2p0, const _Float16* __restrict__ f2p1,
    const _Float16* __restrict__ f2p2, const _Float16* __restrict__ f2p3,
    const int* X0cS, const int* Y0cS, const half8* bf, float* G) {
#pragma unroll
    for (int tt = TB; tt < TE; ++tt) {
        const int L  = tt < 11 ? 0 : tt < 19 ? 1 : tt < 26 ? 2 : 3;
        const int rt = tt - (L == 0 ? 0 : L == 1 ? 11 : L == 2 ? 19 : 26);
        const int Ww = L == 0 ? 13 : L == 1 ? 11 : 10;
        const int MT = L == 0 ? 169 : L == 1 ? 121 : 100;
        const int MAG = L == 0 ? 161320 : L == 1 ? 190652 : 209716;
        const int Wp = L == 0 ? 90 : L == 1 ? 50 : L == 2 ? 30 : 20;
        const int PS = L == 0 ? 259200 : L == 1 ? 80000 : L == 2 ? 28800 : 12800;
        const int PB = L == 0 ? 2073600 : L == 1 ? 640000 : L == 2 ? 230400 : 102400;
        const int GO = L == 0 ? 0 : L == 1 ? 176 : L == 2 ? 304 : 416;
        const _Float16* f2L = (L == 0 ? f2p0 : L == 1 ? f2p1 : L == 2 ? f2p2 : f2p3);
        const _Float16* f2b = f2L + (size_t)b * PB
                            + ((size_t)(Y0cS[L] + 5) * Wp + (X0cS[L] + 5)) * 32;
        int m = min(rt * 16 + (lane & 15), MT - 1);
        int my = (m * MAG) >> 21;
        int mx = m - my * Ww;
        const float4* ap = (const float4*)(f2b + (size_t)(my * Wp + mx) * 32)
                         + (lane >> 4);
        f32x4 acc = {0.f, 0.f, 0.f, 0.f};
#pragma unroll
        for (int kk = 0; kk < 8; ++kk) {
            half8 av = __builtin_bit_cast(half8, ap[kk * (PS / 8)]);
            acc = __builtin_amdgcn_mfma_f32_16x16x32_f16(av, bf[kk], acc, 0, 0, 0);
        }
        int gr = GO + rt * 16 + (lane >> 4) * 4;
#pragma unroll
        for (int r = 0; r < 4; ++r) G[(gr + r) * 17 + (lane & 15)] = acc[r];
    }
}

// ---------- main: per-bucket gather-GEMM ----------
__global__ __launch_bounds__(512, 2) void corr_mfma(
    const _Float16* __restrict__ f1h,
    const _Float16* __restrict__ f2p0, const _Float16* __restrict__ f2p1,
    const _Float16* __restrict__ f2p2, const _Float16* __restrict__ f2p3,
    const float* __restrict__ coords, const int* __restrict__ sortedIdxP,
    _Float16* __restrict__ scratch) {
    __shared__ float G[528 * 17];          // 35.9 KB
    __shared__ _Float16 f1S[16 * 264];     // 8.25 KB, padded stride
    __shared__ float fxS[4][16], fyS[4][16];
    __shared__ int lxS[4][16], lyS[4][16];
    __shared__ int X0cS[4], Y0cS[4], bS;

    int pphys = blockIdx.x;
    int l = (pphys & 7) * 200 + (pphys >> 3);   // XCD swizzle, 1600 % 8 == 0
    int tid = threadIdx.x;
    if (sortedIdxP[l * 16] < 0) return;
    int lane = tid & 63;
    int wave = tid >> 6;

    // stage f1 block: 16 px x 512 B, one coalesced pass by all 512 threads
    {
        int px = tid >> 5, q = tid & 31;
        int n = sortedIdxP[l * 16 + px];
        const float4* src = (const float4*)(f1h + (size_t)n * DCH);
        *((float4*)(f1S + px * 264) + q) = src[q];
    }
    if (tid < 64) {
        int px = tid & 15, Lt = tid >> 4;
        int n = sortedIdxP[l * 16 + px];
        int b = n / 6400;
        int r = n - b * 6400;
        float cx = coords[(size_t)b * 12800 + r];
        float cy = coords[(size_t)b * 12800 + 6400 + r];
        float ls = 1.0f / (float)(1 << Lt);
        float cxl = cx * ls, cyl = cy * ls;
        float fxf = floorf(cxl), fyf = floorf(cyl);
        int X0 = (int)fxf - 4, Y0 = (int)fyf - 4;
        int ix = min(max((int)floorf(cx), 0), 79);
        int iy = min(max((int)floorf(cy), 0), 79);
        int X0c = (((ix >> 2) * 4) >> Lt) - 4;
        int Y0c = (((iy >> 2) * 4) >> Lt) - 4;
        lxS[Lt][px] = min(max(X0 - X0c, 0), 3);
        lyS[Lt][px] = min(max(Y0 - Y0c, 0), 3);
        fxS[Lt][px] = cxl - fxf;
        fyS[Lt][px] = cyl - fyf;
        X0cS[Lt] = X0c;
        Y0cS[Lt] = Y0c;
        if (tid == 0) bS = sortedIdxP[l * 16] / 6400;
    }
    __syncthreads();
    int b = bS;

    // hoist this wave's B fragments from LDS (bank-spread by the +8h pad)
    half8 bf[8];
#pragma unroll
    for (int kk = 0; kk < 8; ++kk)
        bf[kk] = *(const half8*)(f1S + (lane & 15) * 264 + ((lane >> 4) + 4 * kk) * 8);

    // contiguous compile-time tile ranges per wave (33 tiles total)
    if      (wave == 0) run_tiles<0, 5>(lane, b, f2p0, f2p1, f2p2, f2p3, X0cS, Y0cS, bf, G);
    else if (wave == 1) run_tiles<5, 9>(lane, b, f2p0, f2p1, f2p2, f2p3, X0cS, Y0cS, bf, G);
    else if (wave == 2) run_tiles<9, 13>(lane, b, f2p0, f2p1, f2p2, f2p3, X0cS, Y0cS, bf, G);
    else if (wave == 3) run_tiles<13, 17>(lane, b, f2p0, f2p1, f2p2, f2p3, X0cS, Y0cS, bf, G);
    else if (wave == 4) run_tiles<17, 21>(lane, b, f2p0, f2p1, f2p2, f2p3, X0cS, Y0cS, bf, G);
    else if (wave == 5) run_tiles<21, 25>(lane, b, f2p0, f2p1, f2p2, f2p3, X0cS, Y0cS, bf, G);
    else if (wave == 6) run_tiles<25, 29>(lane, b, f2p0, f2p1, f2p2, f2p3, X0cS, Y0cS, bf, G);
    else                run_tiles<29, 33>(lane, b, f2p0, f2p1, f2p2, f2p3, X0cS, Y0cS, bf, G);
    __syncthreads();

    // epilogue: 4 levels x 81 k x 16 slots
    _Float16* sc = scratch + (size_t)l * 5184;
    for (int idx = tid; idx < 5184; idx += 512) {
        int k2 = idx >> 4, x = idx & 15;
        int Le = (k2 * 810) >> 16;            // k2/81, exact for k2<324
        int k = k2 - Le * 81;
        int Ww = Le == 0 ? 13 : Le == 1 ? 11 : 10;
        int GO = Le == 0 ? 0 : Le == 1 ? 176 : Le == 2 ? 304 : 416;
        int a = (k * 57) >> 9;                // k/9, exact for k<=80
        int c = k - 9 * a;
        int gx = lxS[Le][x] + a, gy = lyS[Le][x] + c;
        int m00 = GO + gy * Ww + gx;
        float fx = fxS[Le][x], fy = fyS[Le][x];
        float t00 = G[m00 * 17 + x];
        float t01 = G[(m00 + 1) * 17 + x];
        float t10 = G[(m00 + Ww) * 17 + x];
        float t11 = G[(m00 + Ww + 1) * 17 + x];
        float v = ((1.f - fy) * ((1.f - fx) * t00 + fx * t01)
                 + fy * ((1.f - fx) * t10 + fx * t11)) * 0.0625f;
        sc[idx] = (_Float16)v;
    }
}

// ---------- unsort: scratch[rank[n]] -> out[b][ch][n], float4 stores ----------
__global__ __launch_bounds__(256) void unsort4(const _Float16* __restrict__ scratch,
                                               const int* __restrict__ rank,
                                               float* __restrict__ out) {
    int u = blockIdx.x * 256 + threadIdx.x;   // 2*324*1600 = 1,036,800
    int q = u % 1600;
    int ch = (u / 1600) % 324;
    int b = u / (1600 * 324);
    int nl = q * 4;
    int4 rk = *(const int4*)(rank + b * 6400 + nl);
    float4 v;
    v.x = (float)scratch[(size_t)(rk.x >> 4) * 5184 + ch * 16 + (rk.x & 15)];
    v.y = (float)scratch[(size_t)(rk.y >> 4) * 5184 + ch * 16 + (rk.y & 15)];
    v.z = (float)scratch[(size_t)(rk.z >> 4) * 5184 + ch * 16 + (rk.z & 15)];
    v.w = (float)scratch[(size_t)(rk.w >> 4) * 5184 + ch * 16 + (rk.w & 15)];
    *(float4*)(out + ((size_t)b * 324 + ch) * 6400 + nl) = v;
}

extern "C" void kernel_launch(void* const* d_in, const int* in_sizes, int n_in,
                              void* d_out, int out_size, void* d_ws, size_t ws_size,
                              hipStream_t stream) {
    const float* fmap1 = (const float*)d_in[0];
    const float* fmap2 = (const float*)d_in[1];
    const float* coords = (const float*)d_in[2];
    float* out = (float*)d_out;
    char* ws = (char*)d_ws;

    _Float16* f1h  = (_Float16*)(ws);                  //  6,553,600
    _Float16* f2p0 = (_Float16*)(ws + 6553600);        //  8,294,400 (K-plane, pad 5)
    _Float16* f2p1 = (_Float16*)(ws + 14848000);       //  2,560,000
    _Float16* f2p2 = (_Float16*)(ws + 17408000);       //    921,600
    _Float16* f2p3 = (_Float16*)(ws + 18329600);       //    409,600
    int* sortedIdxP = (int*)(ws + 18739200);           //    102,400 (25600 ints)
    int* rank       = (int*)(ws + 18841600);           //     51,200
    _Float16* scratch = (_Float16*)(ws + 18892800);    // 16,588,800 (total ~35.5 MB)

    // zero all pyramid borders in one shot (buffers contiguous)
    hipMemsetAsync(f2p0, 0, 12185600, stream);

    transpose_all<<<dim3(800), dim3(256), 0, stream>>>(fmap1, fmap2, f1h, f2p0);
    pools<<<dim3(2100), dim3(256), 0, stream>>>(f2p0, f2p1, f2p2, f2p3);
    bucket_k<<<dim3(1), dim3(1024), 0, stream>>>(coords, sortedIdxP, rank);
    corr_mfma<<<dim3(1600), dim3(512), 0, stream>>>(f1h, f2p0, f2p1, f2p2, f2p3,
                                                    coords, sortedIdxP, scratch);
    unsort4<<<dim3(4050), dim3(256), 0, stream>>>(scratch, rank, out);
}

// Round 12
// 97.372 us; speedup vs baseline: 1.6880x; 1.0054x over previous
//
#include <hip/hip_runtime.h>

// RAFT corr block: B=2, D=256, H=W=80, 4 levels, radius 4.
// avg_pool2(corr) over fmap2's spatial dims == corr with avg-pooled fmap2.
// R12: R11 + custom zero-fill kernel. rocclr's fillBufferAligned ran the
// 12.2MB border memset at 271 GB/s (44.5 us, the single largest dispatch!);
// a grid-stride float4 zero kernel does it at HBM speed.

typedef _Float16 h2 __attribute__((ext_vector_type(2)));
typedef _Float16 half8 __attribute__((ext_vector_type(8)));
typedef float f32x4 __attribute__((ext_vector_type(4)));

#define HWDIM 80
#define DCH 256
#define NPIX 12800
#define NBUCKET 800

// ---------- zero fill: 12,185,600 B = 761,600 float4 = 2975 blocks x 256 ----------
__global__ __launch_bounds__(256) void zero_k(float4* __restrict__ dst) {
    int i = blockIdx.x * 256 + threadIdx.x;
    dst[i] = make_float4(0.f, 0.f, 0.f, 0.f);
}

// ---------- fused transpose: f1 -> spatial-major f16; f2 -> K-plane padded ----------
__global__ __launch_bounds__(256) void transpose_all(const float* __restrict__ f1,
                                                     const float* __restrict__ f2,
                                                     _Float16* __restrict__ f1h,
                                                     _Float16* __restrict__ f2p0) {
    __shared__ float tile[256][33];
    int bid = blockIdx.x;
    bool isf1 = bid < 400;
    int lb = isf1 ? bid : bid - 400;
    const float* src = isf1 ? f1 : f2;
    int b = lb / 200;
    int s0 = (lb % 200) * 32;
    int t = threadIdx.x;
    const float* sb = src + (size_t)b * DCH * (HWDIM * HWDIM);
#pragma unroll 4
    for (int k = 0; k < 32; ++k) {
        int j = t + 256 * k;
        int c = j >> 5, s = j & 31;
        tile[c][s] = sb[(size_t)c * (HWDIM * HWDIM) + s0 + s];
    }
    __syncthreads();
    int p = t & 127;
    int srow = t >> 7;
    if (isf1) {
        _Float16* db = f1h + ((size_t)b * 6400 + s0) * DCH;
#pragma unroll 4
        for (int k = 0; k < 16; ++k) {
            int s = 2 * k + srow;
            h2 v;
            v[0] = (_Float16)tile[2 * p][s];
            v[1] = (_Float16)tile[2 * p + 1][s];
            *(h2*)(db + (size_t)s * DCH + 2 * p) = v;
        }
    } else {
#pragma unroll 4
        for (int k = 0; k < 16; ++k) {
            int s = 2 * k + srow;
            int spatial = s0 + s;
            int yy = spatial / 80;
            int xx = spatial - yy * 80;
            h2 v;
            v[0] = (_Float16)tile[2 * p][s];
            v[1] = (_Float16)tile[2 * p + 1][s];
            size_t off = (size_t)b * 2073600 + (size_t)(p >> 4) * 259200
                       + ((size_t)(yy + 5) * 90 + (xx + 5)) * 32 + ((2 * p) & 31);
            *(h2*)(f2p0 + off) = v;
        }
    }
}

// ---------- all pools from L0 directly (one kernel): L1 2x2, L2 4x4, L3 8x8 ----------
__global__ __launch_bounds__(256) void pools(const _Float16* __restrict__ l0,
                                             _Float16* __restrict__ l1,
                                             _Float16* __restrict__ l2,
                                             _Float16* __restrict__ l3) {
    int i = blockIdx.x * 256 + threadIdx.x;      // 409600 + 102400 + 25600 = 537600
    if (i < 409600) {
        int c2 = i & 15;
        int r = i >> 4;
        int x = r % 40; r /= 40;
        int y = r % 40; r /= 40;
        int pl = r & 7;
        int b = r >> 3;
        const h2* s = (const h2*)l0 + (size_t)b * 1036800 + (size_t)pl * 129600
                    + ((size_t)(2 * y + 5) * 90 + (2 * x + 5)) * 16 + c2;
        h2 v00 = s[0], v01 = s[16], v10 = s[90 * 16], v11 = s[90 * 16 + 16];
        float r0 = ((float)v00[0] + (float)v01[0] + (float)v10[0] + (float)v11[0]) * 0.25f;
        float r1 = ((float)v00[1] + (float)v01[1] + (float)v10[1] + (float)v11[1]) * 0.25f;
        h2 o; o[0] = (_Float16)r0; o[1] = (_Float16)r1;
        *((h2*)l1 + (size_t)b * 320000 + (size_t)pl * 40000
          + ((size_t)(y + 5) * 50 + (x + 5)) * 16 + c2) = o;
    } else if (i < 512000) {
        int j = i - 409600;
        int c2 = j & 15;
        int r = j >> 4;
        int x = r % 20; r /= 20;
        int y = r % 20; r /= 20;
        int pl = r & 7;
        int b = r >> 3;
        const h2* s = (const h2*)l0 + (size_t)b * 1036800 + (size_t)pl * 129600 + c2;
        float r0 = 0.f, r1 = 0.f;
#pragma unroll
        for (int dy = 0; dy < 4; ++dy)
#pragma unroll
            for (int dx = 0; dx < 4; ++dx) {
                h2 v = s[((size_t)(4 * y + dy + 5) * 90 + (4 * x + dx + 5)) * 16];
                r0 += (float)v[0];
                r1 += (float)v[1];
            }
        h2 o; o[0] = (_Float16)(r0 * 0.0625f); o[1] = (_Float16)(r1 * 0.0625f);
        *((h2*)l2 + (size_t)b * 115200 + (size_t)pl * 14400
          + ((size_t)(y + 5) * 30 + (x + 5)) * 16 + c2) = o;
    } else {
        int j = i - 512000;
        int c2 = j & 15;
        int r = j >> 4;
        int x = r % 10; r /= 10;
        int y = r % 10; r /= 10;
        int pl = r & 7;
        int b = r >> 3;
        const h2* s = (const h2*)l0 + (size_t)b * 1036800 + (size_t)pl * 129600 + c2;
        float r0 = 0.f, r1 = 0.f;
#pragma unroll
        for (int dy = 0; dy < 8; ++dy)
#pragma unroll
            for (int dx = 0; dx < 8; ++dx) {
                h2 v = s[((size_t)(8 * y + dy + 5) * 90 + (8 * x + dx + 5)) * 16];
                r0 += (float)v[0];
                r1 += (float)v[1];
            }
        h2 o; o[0] = (_Float16)(r0 * 0.015625f); o[1] = (_Float16)(r1 * 0.015625f);
        *((h2*)l3 + (size_t)b * 51200 + (size_t)pl * 6400
          + ((size_t)(y + 5) * 20 + (x + 5)) * 16 + c2) = o;
    }
}

// ---------- single-block bucket sort: hist + shfl-scan + scatter + fill + sentinel ----------
static __device__ __forceinline__ int bucket_of(const float* coords, int n) {
    int b = n / 6400;
    int r = n - b * 6400;
    float cx = coords[(size_t)b * 12800 + r];
    float cy = coords[(size_t)b * 12800 + 6400 + r];
    int ix = min(max((int)floorf(cx), 0), 79);
    int iy = min(max((int)floorf(cy), 0), 79);
    return b * 400 + (iy >> 2) * 20 + (ix >> 2);
}

__global__ __launch_bounds__(1024) void bucket_k(const float* __restrict__ coords,
                                                 int* __restrict__ sortedIdxP,
                                                 int* __restrict__ rank) {
    __shared__ unsigned int histS[NBUCKET], startS[NBUCKET], curS[NBUCKET];
    __shared__ unsigned int waveSum[16];
    __shared__ unsigned int totalS;
    int t = threadIdx.x;
    if (t < NBUCKET) histS[t] = 0u;
    __syncthreads();
    int bkt[13];
#pragma unroll
    for (int i = 0; i < 13; ++i) {
        int n = i * 1024 + t;
        if (n < NPIX) {
            bkt[i] = bucket_of(coords, n);
            atomicAdd(&histS[bkt[i]], 1u);
        }
    }
    __syncthreads();
    unsigned int v = (t < NBUCKET) ? ((histS[t] + 15u) & ~15u) : 0u;
    unsigned int x = v;
#pragma unroll
    for (int d = 1; d < 64; d <<= 1) {
        unsigned int y = __shfl_up(x, d);
        if ((t & 63) >= d) x += y;
    }
    if ((t & 63) == 63) waveSum[t >> 6] = x;
    __syncthreads();
    if (t < 16) {
        unsigned int w = waveSum[t];
#pragma unroll
        for (int d = 1; d < 16; d <<= 1) {
            unsigned int y = __shfl_up(w, d);
            if (t >= d) w += y;
        }
        waveSum[t] = w;
    }
    __syncthreads();
    unsigned int incl = x + ((t >> 6) ? waveSum[(t >> 6) - 1] : 0u);
    if (t < NBUCKET) {
        unsigned int e = incl - v;
        startS[t] = e;
        curS[t] = e;
        if (t == NBUCKET - 1) totalS = incl;
    }
    __syncthreads();
#pragma unroll
    for (int i = 0; i < 13; ++i) {
        int n = i * 1024 + t;
        if (n < NPIX) {
            unsigned int pos = atomicAdd(&curS[bkt[i]], 1u);
            sortedIdxP[pos] = n;
            rank[n] = (int)pos;
        }
    }
    __syncthreads();
    if (t < NBUCKET) {
        unsigned int h = histS[t];
        if (h) {
            unsigned int pc = (h + 15u) & ~15u;
            unsigned int base = startS[t];
            int dup = sortedIdxP[base];
            for (unsigned int s = h; s < pc; ++s) sortedIdxP[base + s] = dup;
        }
    }
    // sentinels for unused padded slots (replaces a 0xFF memset dispatch)
    for (unsigned int s = totalS + t; s < 25600u; s += 1024u) sortedIdxP[s] = -1;
}

// ---------- per-wave straight-line tile runner (compile-time range) ----------
template <int TB, int TE>
static __device__ __forceinline__ void run_tiles(
    int lane, int b,
    const _Float16* __restrict__ f2p0, const _Float16* __restrict__ f2p1,
    const _Float16* __restrict__ f2p2, const _Float16* __restrict__ f2p3,
    const int* X0cS, const int* Y0cS, const half8* bf, float* G) {
#pragma unroll
    for (int tt = TB; tt < TE; ++tt) {
        const int L  = tt < 11 ? 0 : tt < 19 ? 1 : tt < 26 ? 2 : 3;
        const int rt = tt - (L == 0 ? 0 : L == 1 ? 11 : L == 2 ? 19 : 26);
        const int Ww = L == 0 ? 13 : L == 1 ? 11 : 10;
        const int MT = L == 0 ? 169 : L == 1 ? 121 : 100;
        const int MAG = L == 0 ? 161320 : L == 1 ? 190652 : 209716;
        const int Wp = L == 0 ? 90 : L == 1 ? 50 : L == 2 ? 30 : 20;
        const int PS = L == 0 ? 259200 : L == 1 ? 80000 : L == 2 ? 28800 : 12800;
        const int PB = L == 0 ? 2073600 : L == 1 ? 640000 : L == 2 ? 230400 : 102400;
        const int GO = L == 0 ? 0 : L == 1 ? 176 : L == 2 ? 304 : 416;
        const _Float16* f2L = (L == 0 ? f2p0 : L == 1 ? f2p1 : L == 2 ? f2p2 : f2p3);
        const _Float16* f2b = f2L + (size_t)b * PB
                            + ((size_t)(Y0cS[L] + 5) * Wp + (X0cS[L] + 5)) * 32;
        int m = min(rt * 16 + (lane & 15), MT - 1);
        int my = (m * MAG) >> 21;
        int mx = m - my * Ww;
        const float4* ap = (const float4*)(f2b + (size_t)(my * Wp + mx) * 32)
                         + (lane >> 4);
        f32x4 acc = {0.f, 0.f, 0.f, 0.f};
#pragma unroll
        for (int kk = 0; kk < 8; ++kk) {
            half8 av = __builtin_bit_cast(half8, ap[kk * (PS / 8)]);
            acc = __builtin_amdgcn_mfma_f32_16x16x32_f16(av, bf[kk], acc, 0, 0, 0);
        }
        int gr = GO + rt * 16 + (lane >> 4) * 4;
#pragma unroll
        for (int r = 0; r < 4; ++r) G[(gr + r) * 17 + (lane & 15)] = acc[r];
    }
}

// ---------- main: per-bucket gather-GEMM ----------
__global__ __launch_bounds__(512, 2) void corr_mfma(
    const _Float16* __restrict__ f1h,
    const _Float16* __restrict__ f2p0, const _Float16* __restrict__ f2p1,
    const _Float16* __restrict__ f2p2, const _Float16* __restrict__ f2p3,
    const float* __restrict__ coords, const int* __restrict__ sortedIdxP,
    _Float16* __restrict__ scratch) {
    __shared__ float G[528 * 17];          // 35.9 KB
    __shared__ _Float16 f1S[16 * 264];     // 8.25 KB, padded stride
    __shared__ float fxS[4][16], fyS[4][16];
    __shared__ int lxS[4][16], lyS[4][16];
    __shared__ int X0cS[4], Y0cS[4], bS;

    int pphys = blockIdx.x;
    int l = (pphys & 7) * 200 + (pphys >> 3);   // XCD swizzle, 1600 % 8 == 0
    int tid = threadIdx.x;
    if (sortedIdxP[l * 16] < 0) return;
    int lane = tid & 63;
    int wave = tid >> 6;

    // stage f1 block: 16 px x 512 B, one coalesced pass by all 512 threads
    {
        int px = tid >> 5, q = tid & 31;
        int n = sortedIdxP[l * 16 + px];
        const float4* src = (const float4*)(f1h + (size_t)n * DCH);
        *((float4*)(f1S + px * 264) + q) = src[q];
    }
    if (tid < 64) {
        int px = tid & 15, Lt = tid >> 4;
        int n = sortedIdxP[l * 16 + px];
        int b = n / 6400;
        int r = n - b * 6400;
        float cx = coords[(size_t)b * 12800 + r];
        float cy = coords[(size_t)b * 12800 + 6400 + r];
        float ls = 1.0f / (float)(1 << Lt);
        float cxl = cx * ls, cyl = cy * ls;
        float fxf = floorf(cxl), fyf = floorf(cyl);
        int X0 = (int)fxf - 4, Y0 = (int)fyf - 4;
        int ix = min(max((int)floorf(cx), 0), 79);
        int iy = min(max((int)floorf(cy), 0), 79);
        int X0c = (((ix >> 2) * 4) >> Lt) - 4;
        int Y0c = (((iy >> 2) * 4) >> Lt) - 4;
        lxS[Lt][px] = min(max(X0 - X0c, 0), 3);
        lyS[Lt][px] = min(max(Y0 - Y0c, 0), 3);
        fxS[Lt][px] = cxl - fxf;
        fyS[Lt][px] = cyl - fyf;
        X0cS[Lt] = X0c;
        Y0cS[Lt] = Y0c;
        if (tid == 0) bS = sortedIdxP[l * 16] / 6400;
    }
    __syncthreads();
    int b = bS;

    // hoist this wave's B fragments from LDS (bank-spread by the +8h pad)
    half8 bf[8];
#pragma unroll
    for (int kk = 0; kk < 8; ++kk)
        bf[kk] = *(const half8*)(f1S + (lane & 15) * 264 + ((lane >> 4) + 4 * kk) * 8);

    // contiguous compile-time tile ranges per wave (33 tiles total)
    if      (wave == 0) run_tiles<0, 5>(lane, b, f2p0, f2p1, f2p2, f2p3, X0cS, Y0cS, bf, G);
    else if (wave == 1) run_tiles<5, 9>(lane, b, f2p0, f2p1, f2p2, f2p3, X0cS, Y0cS, bf, G);
    else if (wave == 2) run_tiles<9, 13>(lane, b, f2p0, f2p1, f2p2, f2p3, X0cS, Y0cS, bf, G);
    else if (wave == 3) run_tiles<13, 17>(lane, b, f2p0, f2p1, f2p2, f2p3, X0cS, Y0cS, bf, G);
    else if (wave == 4) run_tiles<17, 21>(lane, b, f2p0, f2p1, f2p2, f2p3, X0cS, Y0cS, bf, G);
    else if (wave == 5) run_tiles<21, 25>(lane, b, f2p0, f2p1, f2p2, f2p3, X0cS, Y0cS, bf, G);
    else if (wave == 6) run_tiles<25, 29>(lane, b, f2p0, f2p1, f2p2, f2p3, X0cS, Y0cS, bf, G);
    else                run_tiles<29, 33>(lane, b, f2p0, f2p1, f2p2, f2p3, X0cS, Y0cS, bf, G);
    __syncthreads();

    // epilogue: 4 levels x 81 k x 16 slots
    _Float16* sc = scratch + (size_t)l * 5184;
    for (int idx = tid; idx < 5184; idx += 512) {
        int k2 = idx >> 4, x = idx & 15;
        int Le = (k2 * 810) >> 16;            // k2/81, exact for k2<324
        int k = k2 - Le * 81;
        int Ww = Le == 0 ? 13 : Le == 1 ? 11 : 10;
        int GO = Le == 0 ? 0 : Le == 1 ? 176 : Le == 2 ? 304 : 416;
        int a = (k * 57) >> 9;                // k/9, exact for k<=80
        int c = k - 9 * a;
        int gx = lxS[Le][x] + a, gy = lyS[Le][x] + c;
        int m00 = GO + gy * Ww + gx;
        float fx = fxS[Le][x], fy = fyS[Le][x];
        float t00 = G[m00 * 17 + x];
        float t01 = G[(m00 + 1) * 17 + x];
        float t10 = G[(m00 + Ww) * 17 + x];
        float t11 = G[(m00 + Ww + 1) * 17 + x];
        float v = ((1.f - fy) * ((1.f - fx) * t00 + fx * t01)
                 + fy * ((1.f - fx) * t10 + fx * t11)) * 0.0625f;
        sc[idx] = (_Float16)v;
    }
}

// ---------- unsort: scratch[rank[n]] -> out[b][ch][n], float4 stores ----------
__global__ __launch_bounds__(256) void unsort4(const _Float16* __restrict__ scratch,
                                               const int* __restrict__ rank,
                                               float* __restrict__ out) {
    int u = blockIdx.x * 256 + threadIdx.x;   // 2*324*1600 = 1,036,800
    int q = u % 1600;
    int ch = (u / 1600) % 324;
    int b = u / (1600 * 324);
    int nl = q * 4;
    int4 rk = *(const int4*)(rank + b * 6400 + nl);
    float4 v;
    v.x = (float)scratch[(size_t)(rk.x >> 4) * 5184 + ch * 16 + (rk.x & 15)];
    v.y = (float)scratch[(size_t)(rk.y >> 4) * 5184 + ch * 16 + (rk.y & 15)];
    v.z = (float)scratch[(size_t)(rk.z >> 4) * 5184 + ch * 16 + (rk.z & 15)];
    v.w = (float)scratch[(size_t)(rk.w >> 4) * 5184 + ch * 16 + (rk.w & 15)];
    *(float4*)(out + ((size_t)b * 324 + ch) * 6400 + nl) = v;
}

extern "C" void kernel_launch(void* const* d_in, const int* in_sizes, int n_in,
                              void* d_out, int out_size, void* d_ws, size_t ws_size,
                              hipStream_t stream) {
    const float* fmap1 = (const float*)d_in[0];
    const float* fmap2 = (const float*)d_in[1];
    const float* coords = (const float*)d_in[2];
    float* out = (float*)d_out;
    char* ws = (char*)d_ws;

    _Float16* f1h  = (_Float16*)(ws);                  //  6,553,600
    _Float16* f2p0 = (_Float16*)(ws + 6553600);        //  8,294,400 (K-plane, pad 5)
    _Float16* f2p1 = (_Float16*)(ws + 14848000);       //  2,560,000
    _Float16* f2p2 = (_Float16*)(ws + 17408000);       //    921,600
    _Float16* f2p3 = (_Float16*)(ws + 18329600);       //    409,600
    int* sortedIdxP = (int*)(ws + 18739200);           //    102,400 (25600 ints)
    int* rank       = (int*)(ws + 18841600);           //     51,200
    _Float16* scratch = (_Float16*)(ws + 18892800);    // 16,588,800 (total ~35.5 MB)

    // zero all pyramid buffers (borders survive; interiors overwritten later)
    zero_k<<<dim3(2975), dim3(256), 0, stream>>>((float4*)f2p0);

    transpose_all<<<dim3(800), dim3(256), 0, stream>>>(fmap1, fmap2, f1h, f2p0);
    pools<<<dim3(2100), dim3(256), 0, stream>>>(f2p0, f2p1, f2p2, f2p3);
    bucket_k<<<dim3(1), dim3(1024), 0, stream>>>(coords, sortedIdxP, rank);
    corr_mfma<<<dim3(1600), dim3(512), 0, stream>>>(f1h, f2p0, f2p1, f2p2, f2p3,
                                                    coords, sortedIdxP, scratch);
    unsort4<<<dim3(4050), dim3(256), 0, stream>>>(scratch, rank, out);
}